// Round 8
// baseline (4405.172 us; speedup 1.0000x reference)
//
#include <hip/hip_runtime.h>
#include <math.h>

// ---- problem constants ----
#define C_      3
#define H_      224
#define W_      224
#define KH_     14
#define KW_     14
#define NPATCH  196
#define PELEMS  768
#define D_      768
#define HEADS_  12
#define Y_      64
#define MHID    3072
#define NMASK   100
#define NSTEPS  12
#define ALPHA_  0.1f
#define BETA_   0.125f
#define EPS_    1e-5f
#define B_      16
#define NTOK    197
#define ROWS    (B_*NTOK)   /* 3152 real rows */
#define MPAD    3200        /* 25 * 128 */
#define QKLD    1536        /* fused q|k leading dim */
#define PACKLD  4608        /* hid(3072) | Gq(768) | Gk(768) */
#define W2LD    4608        /* qk(1536) | hid(3072) fused B rows */
#define PGP     208         /* global P pitch (bf16), 13*16 */
#define KSPLIT  4           /* grad GEMM split-K factor */

typedef short short8 __attribute__((ext_vector_type(8)));
typedef unsigned short ushort8 __attribute__((ext_vector_type(8)));
typedef float floatx4 __attribute__((ext_vector_type(4)));

__device__ __forceinline__ unsigned short f2bf(float f) {
    union { float f; unsigned u; } v; v.f = f;
    unsigned r = (v.u + 0x7FFFu + ((v.u >> 16) & 1u)) >> 16;
    return (unsigned short)r;
}
__device__ __forceinline__ float bf2f(unsigned short u) {
    union { unsigned u; float f; } v; v.u = ((unsigned)u) << 16;
    return v.f;
}

// ---------------------------------------------------------------------------
// MFMA bf16 NT GEMM: C[M][N] = A(MxK bf16) @ B(NxK bf16)^T,  BK=64/iter.
// K-loop uses global->register->LDS pipeline: chunk k+1 loads issue during
// chunk k's MFMAs; the vmcnt wait lands at next iteration's ds_write, not at
// the barrier (registers are private), hiding HBM/L2 latency.
// OUT_MODE: 0 = fp32 store, 1 = bf16 store,
//           3 = split epilogue (col<1536 -> Cout bf16 ld QKLD, else relu ->
//               Cout2 bf16 ld PACKLD) with XCD-rectangle swizzle (1D grid 1024),
//           4 = split-K: koff = blockIdx.z*K, atomicAdd(Cout, ALPHA*v) fp32
template<int OUT_MODE, bool RELU, bool HAS_BIAS>
__global__ __launch_bounds__(256) void mfma_gemm(
    const unsigned short* __restrict__ A, int lda,
    const unsigned short* __restrict__ B, int ldb,
    void* __restrict__ Cout, int ldc, void* __restrict__ Cout2,
    const float* __restrict__ bias, int K)
{
    __shared__ alignas(16) unsigned short ldsA[2][128 * 32];
    __shared__ alignas(16) unsigned short ldsB[2][128 * 32];

    int bx, by, koff = 0;
    if (OUT_MODE == 3) {
        int lin = blockIdx.x;
        int xcd = lin & 7, s = lin >> 3;
        int rg = xcd >> 1, cg = xcd & 1;
        int rs = (rg == 0) ? 7 : 6;
        int rstart = (rg == 0) ? 0 : (6 * rg + 1);
        if (s >= rs * 18) return;
        by = rstart + s % rs;
        bx = cg * 18 + s / rs;
    } else {
        bx = blockIdx.x; by = blockIdx.y;
        if (OUT_MODE == 4) koff = blockIdx.z * K;
    }

    const int t    = threadIdx.x;
    const int wave = t >> 6;
    const int lane = t & 63;
    const int row0 = by << 7;
    const int col0 = bx << 7;
    const int wm = (wave & 1) << 6;
    const int wn = (wave >> 1) << 6;
    const int r  = lane & 15;
    const int qd = lane >> 4;

    const unsigned short* Abase = A + (size_t)row0 * lda + koff;
    const unsigned short* Bbase = B + (size_t)col0 * ldb + koff;

    floatx4 acc[4][4];
#pragma unroll
    for (int i = 0; i < 4; ++i)
#pragma unroll
        for (int j = 0; j < 4; ++j)
            acc[i][j] = (floatx4){0.f, 0.f, 0.f, 0.f};

    // staging decomposition (128 rows x 64 K per buffer pair):
    // thread t handles 16B chunks at rows rbase+{0,32,64,96}, k-sub 'sub'.
    const int sub   = t & 7;            // which 8-elem group within the 64-K row
    const int rbase = t >> 3;           // row 0..31
    const int kb_w  = sub >> 2;         // which 32-K half-buffer
    const int klo   = (sub & 3) << 3;   // elem offset within half-buffer row

    uint4 pa[4], pb[4];
#pragma unroll
    for (int i = 0; i < 4; ++i) {
        int row = rbase + (i << 5);
        pa[i] = *(const uint4*)(Abase + (size_t)row * lda + sub * 8);
        pb[i] = *(const uint4*)(Bbase + (size_t)row * ldb + sub * 8);
    }

    for (int k0 = 0; k0 < K; k0 += 64) {
        // commit prefetched chunk to LDS
#pragma unroll
        for (int i = 0; i < 4; ++i) {
            int row = rbase + (i << 5);
            *(uint4*)&ldsA[kb_w][row * 32 + klo] = pa[i];
            *(uint4*)&ldsB[kb_w][row * 32 + klo] = pb[i];
        }
        __syncthreads();
        // issue next chunk's loads (consumed next iteration)
        if (k0 + 64 < K) {
#pragma unroll
            for (int i = 0; i < 4; ++i) {
                int row = rbase + (i << 5);
                pa[i] = *(const uint4*)(Abase + (size_t)row * lda + k0 + 64 + sub * 8);
                pb[i] = *(const uint4*)(Bbase + (size_t)row * ldb + k0 + 64 + sub * 8);
            }
        }
        // compute on the two 32-K half-buffers
#pragma unroll
        for (int kb = 0; kb < 2; ++kb) {
            short8 af[4], bfr[4];
#pragma unroll
            for (int i = 0; i < 4; ++i) {
                af[i]  = *(const short8*)&ldsA[kb][(wm + (i << 4) + r) * 32 + (qd << 3)];
                bfr[i] = *(const short8*)&ldsB[kb][(wn + (i << 4) + r) * 32 + (qd << 3)];
            }
#pragma unroll
            for (int i = 0; i < 4; ++i)
#pragma unroll
                for (int j = 0; j < 4; ++j)
                    acc[i][j] = __builtin_amdgcn_mfma_f32_16x16x32_bf16(
                                    af[i], bfr[j], acc[i][j], 0, 0, 0);
        }
        __syncthreads();
    }

#pragma unroll
    for (int i = 0; i < 4; ++i) {
#pragma unroll
        for (int j = 0; j < 4; ++j) {
            int cc = col0 + wn + (j << 4) + r;
#pragma unroll
            for (int reg = 0; reg < 4; ++reg) {
                int rr = row0 + wm + (i << 4) + (qd << 2) + reg;
                float v = acc[i][j][reg];
                if (HAS_BIAS) v += bias[cc];
                if (RELU)     v = fmaxf(v, 0.f);
                if (OUT_MODE == 1)
                    ((unsigned short*)Cout)[(size_t)rr * ldc + cc] = f2bf(v);
                else if (OUT_MODE == 3) {
                    if (cc < QKLD)
                        ((unsigned short*)Cout)[(size_t)rr * QKLD + cc] = f2bf(v);
                    else
                        ((unsigned short*)Cout2)[(size_t)rr * PACKLD + (cc - QKLD)]
                            = f2bf(fmaxf(v, 0.f));
                } else if (OUT_MODE == 4)
                    atomicAdd(&((float*)Cout)[(size_t)rr * ldc + cc], ALPHA_ * v);
                else
                    ((float*)Cout)[(size_t)rr * ldc + cc] = v;
            }
        }
    }
}

// ---------------------------------------------------------------------------
// Attention A: per (bh, 32-q-row chunk): S = Q K^T via MFMA, softmax (beta in
// exp), P -> global bf16 (pitch 208, pad cols zero), Gq -> pack cols 3072+.
__global__ __launch_bounds__(256) void attn_pgq_kernel(
    const unsigned short* __restrict__ qk,   // bf16 [MPAD][1536]
    unsigned short* __restrict__ Pg,         // bf16 [192*197][208]
    unsigned short* __restrict__ pack)
{
    const int bh = blockIdx.x;
    const int h = bh % HEADS_, b = bh / HEADS_;
    const int n0 = blockIdx.y << 5;
    const int csz = (NTOK - n0 < 32) ? (NTOK - n0) : 32;
    const int t = threadIdx.x;
    const int lane = t & 63, wave = t >> 6;
    const int ln15 = lane & 15, quad = lane >> 4;

    __shared__ alignas(16) unsigned short KsS[208 * 72];  // K_h m-major
    __shared__ alignas(16) unsigned short QcS[32 * 72];   // Q chunk
    __shared__ alignas(16) float Pm[32 * 224];            // S/P fp32

    const size_t rowbase = (size_t)(b * NTOK) * QKLD;
    const int hoff = h * 64;

    for (int idx = t; idx < NTOK * 8; idx += 256) {
        int m = idx >> 3, c8 = idx & 7;
        *(uint4*)&KsS[m * 72 + c8 * 8] =
            *(const uint4*)&qk[rowbase + (size_t)m * QKLD + 768 + hoff + c8 * 8];
    }
    for (int idx = t; idx < 88; idx += 256) {
        int m = 197 + (idx >> 3), c8 = idx & 7;
        *(uint4*)&KsS[m * 72 + c8 * 8] = (uint4){0, 0, 0, 0};
    }
    for (int idx = t; idx < csz * 8; idx += 256) {
        int nn = idx >> 3, c8 = idx & 7;
        *(uint4*)&QcS[nn * 72 + c8 * 8] =
            *(const uint4*)&qk[rowbase + (size_t)(n0 + nn) * QKLD + hoff + c8 * 8];
    }
    __syncthreads();

    // ---- S = Q K^T via MFMA ----
    {
        short8 aq[2][2];
#pragma unroll
        for (int mt = 0; mt < 2; ++mt)
#pragma unroll
            for (int kb = 0; kb < 2; ++kb)
                aq[mt][kb] = *(const short8*)
                    &QcS[(mt * 16 + ln15) * 72 + kb * 32 + quad * 8];

        for (int nt = wave; nt < 13; nt += 4) {
            short8 b0 = *(const short8*)&KsS[(nt * 16 + ln15) * 72 + quad * 8];
            short8 b1 = *(const short8*)&KsS[(nt * 16 + ln15) * 72 + 32 + quad * 8];
            floatx4 s0 = (floatx4){0.f, 0.f, 0.f, 0.f};
            floatx4 s1 = (floatx4){0.f, 0.f, 0.f, 0.f};
            s0 = __builtin_amdgcn_mfma_f32_16x16x32_bf16(aq[0][0], b0, s0, 0, 0, 0);
            s0 = __builtin_amdgcn_mfma_f32_16x16x32_bf16(aq[0][1], b1, s0, 0, 0, 0);
            s1 = __builtin_amdgcn_mfma_f32_16x16x32_bf16(aq[1][0], b0, s1, 0, 0, 0);
            s1 = __builtin_amdgcn_mfma_f32_16x16x32_bf16(aq[1][1], b1, s1, 0, 0, 0);
#pragma unroll
            for (int reg = 0; reg < 4; ++reg) {
                Pm[(quad * 4 + reg) * 224 + nt * 16 + ln15]        = s0[reg];
                Pm[(16 + quad * 4 + reg) * 224 + nt * 16 + ln15]   = s1[reg];
            }
        }
    }
    __syncthreads();

    // ---- softmax rows (beta applied inside exp) ----
    for (int nn = wave; nn < csz; nn += 4) {
        float v0 = Pm[nn * 224 + lane];
        float v1 = (lane +  64 < NTOK) ? Pm[nn * 224 + lane +  64] : -1e30f;
        float v2 = (lane + 128 < NTOK) ? Pm[nn * 224 + lane + 128] : -1e30f;
        float v3 = (lane + 192 < NTOK) ? Pm[nn * 224 + lane + 192] : -1e30f;
        float mx = fmaxf(fmaxf(v0, v1), fmaxf(v2, v3));
#pragma unroll
        for (int o = 32; o > 0; o >>= 1) mx = fmaxf(mx, __shfl_xor(mx, o, 64));
        float e0 = __expf((v0 - mx) * BETA_);
        float e1 = (lane +  64 < NTOK) ? __expf((v1 - mx) * BETA_) : 0.f;
        float e2 = (lane + 128 < NTOK) ? __expf((v2 - mx) * BETA_) : 0.f;
        float e3 = (lane + 192 < NTOK) ? __expf((v3 - mx) * BETA_) : 0.f;
        float s = e0 + e1 + e2 + e3;
#pragma unroll
        for (int o = 32; o > 0; o >>= 1) s += __shfl_xor(s, o, 64);
        float inv = 1.0f / s;
        Pm[nn * 224 + lane] = e0 * inv;
        if (lane +  64 < NTOK) Pm[nn * 224 + lane +  64] = e1 * inv;
        if (lane + 128 < NTOK) Pm[nn * 224 + lane + 128] = e2 * inv;
        if (lane + 192 < NTOK) Pm[nn * 224 + lane + 192] = e3 * inv;
    }
    __syncthreads();

    // ---- write P (bf16, pad cols 197..207 = 0) ----
    if (t < PGP) {
        for (int nn = 0; nn < csz; ++nn) {
            unsigned short v = (t < NTOK) ? f2bf(Pm[nn * 224 + t]) : (unsigned short)0;
            Pg[((size_t)bh * NTOK + n0 + nn) * PGP + t] = v;
        }
    }

    // ---- Gq[n][y] = sum_m P[n][m] K[m][y] ----
    {
        const int y = lane;
        const int rbase2 = wave * 8;
        float gq[8] = {0.f, 0.f, 0.f, 0.f, 0.f, 0.f, 0.f, 0.f};
        for (int m0 = 0; m0 < 200; m0 += 4) {
            float kv0 = bf2f(KsS[(m0 + 0) * 72 + y]);
            float kv1 = bf2f(KsS[(m0 + 1) * 72 + y]);
            float kv2 = bf2f(KsS[(m0 + 2) * 72 + y]);
            float kv3 = bf2f(KsS[(m0 + 3) * 72 + y]);
#pragma unroll
            for (int i2 = 0; i2 < 8; ++i2) {
                const float4 pv = *(const float4*)&Pm[(rbase2 + i2) * 224 + m0];
                gq[i2] += pv.x * kv0 + pv.y * kv1 + pv.z * kv2 + pv.w * kv3;
            }
        }
#pragma unroll
        for (int i2 = 0; i2 < 8; ++i2) {
            int nn = rbase2 + i2;
            if (nn < csz)
                pack[(size_t)(b * NTOK + n0 + nn) * PACKLD + 3072 + hoff + y]
                    = f2bf(gq[i2]);
        }
    }
}

// ---------------------------------------------------------------------------
// Attention B: per (bh, 64-m chunk): Gk[m][y] = sum_n P[n][m] Q[n][y]
__global__ __launch_bounds__(256) void attn_gk_kernel(
    const unsigned short* __restrict__ qk,
    const unsigned short* __restrict__ Pg,
    unsigned short* __restrict__ pack)
{
    const int bh = blockIdx.x;
    const int h = bh % HEADS_, b = bh / HEADS_;
    const int m0 = blockIdx.y << 6;
    const int t = threadIdx.x;
    const int y = t & 63, mg = t >> 6;

    __shared__ alignas(16) unsigned short Qs[NTOK * 72];
    __shared__ alignas(16) unsigned short Ps[32 * 64];

    const size_t rowbase = (size_t)(b * NTOK) * QKLD;
    const int hoff = h * 64;
    for (int idx = t; idx < NTOK * 8; idx += 256) {
        int n = idx >> 3, c8 = idx & 7;
        *(uint4*)&Qs[n * 72 + c8 * 8] =
            *(const uint4*)&qk[rowbase + (size_t)n * QKLD + hoff + c8 * 8];
    }

    float gk[16] = {0.f, 0.f, 0.f, 0.f, 0.f, 0.f, 0.f, 0.f,
                    0.f, 0.f, 0.f, 0.f, 0.f, 0.f, 0.f, 0.f};

    for (int nc = 0; nc < NTOK; nc += 32) {
        int csz = (NTOK - nc < 32) ? (NTOK - nc) : 32;
        __syncthreads();
        for (int idx = t; idx < csz * 8; idx += 256) {
            int nn = idx >> 3, c8 = idx & 7;
            uint4 v = (uint4){0, 0, 0, 0};
            if (m0 + c8 * 8 < PGP)
                v = *(const uint4*)&Pg[((size_t)bh * NTOK + nc + nn) * PGP + m0 + c8 * 8];
            *(uint4*)&Ps[nn * 64 + c8 * 8] = v;
        }
        __syncthreads();
        for (int nn = 0; nn < csz; ++nn) {
            float qv = bf2f(Qs[(nc + nn) * 72 + y]);
            ushort8 p0 = *(const ushort8*)&Ps[nn * 64 + mg * 16];
            ushort8 p1 = *(const ushort8*)&Ps[nn * 64 + mg * 16 + 8];
#pragma unroll
            for (int j = 0; j < 8; ++j) gk[j]     += bf2f(p0[j]) * qv;
#pragma unroll
            for (int j = 0; j < 8; ++j) gk[8 + j] += bf2f(p1[j]) * qv;
        }
    }

#pragma unroll
    for (int j = 0; j < 16; ++j) {
        int m = m0 + mg * 16 + j;
        if (m < NTOK)
            pack[(size_t)(b * NTOK + m) * PACKLD + 3840 + hoff + y] = f2bf(gk[j]);
    }
}

// ---------------------------------------------------------------------------
// setup conversions
__global__ __launch_bounds__(256) void w2pack_kernel(const float* __restrict__ Wq,
                                                     const float* __restrict__ Wk,
                                                     const float* __restrict__ Xi,
                                                     unsigned short* __restrict__ out)
{
    int idx = blockIdx.x * 256 + threadIdx.x;          // n*768 + d
    int d = idx % D_, n = idx / D_;
    float v;
    if (n < 768)       v = Wq[((size_t)(n >> 6) * D_ + d) * Y_ + (n & 63)];
    else if (n < 1536) { int e = n - 768; v = Wk[((size_t)(e >> 6) * D_ + d) * Y_ + (e & 63)]; }
    else               v = Xi[(size_t)d * MHID + (n - 1536)];
    out[idx] = f2bf(v);
}

__global__ __launch_bounds__(256) void bpack_kernel(const float* __restrict__ Xi,
                                                    const float* __restrict__ Wq,
                                                    const float* __restrict__ Wk,
                                                    unsigned short* __restrict__ out)
{
    int idx = blockIdx.x * 256 + threadIdx.x;          // d*4608 + c
    int c = idx % PACKLD, d = idx / PACKLD;
    float v;
    if (c < 3072)       v = Xi[(size_t)d * MHID + c];
    else if (c < 3840)  { int e = c - 3072; v = Wq[((size_t)(e >> 6) * D_ + d) * Y_ + (e & 63)]; }
    else                { int e = c - 3840; v = Wk[((size_t)(e >> 6) * D_ + d) * Y_ + (e & 63)]; }
    out[idx] = f2bf(v);
}

__global__ __launch_bounds__(256) void t768_kernel(const float* __restrict__ in,
                                                   unsigned short* __restrict__ out)
{
    int idx = blockIdx.x * 256 + threadIdx.x;          // n*768 + k
    int k = idx % D_, n = idx / D_;
    out[idx] = f2bf(in[(size_t)k * D_ + n]);
}

// ---------------------------------------------------------------------------
__global__ void mask_flags_kernel(const int* __restrict__ mask, int* __restrict__ flags)
{
    int b = threadIdx.x;
    if (b >= B_) return;
    const int* mb = mask + b * NPATCH;
    int* fb = flags + b * NPATCH;
    int cnt = 0;
    for (int n = 0; n < NPATCH; ++n) {
        int mv = mb[n];
        fb[n] = (mv == 1 && cnt < NMASK) ? 1 : 0;
        cnt += (mv == 1);
    }
    if (cnt < NMASK) fb[0] = 1;
}

__global__ __launch_bounds__(256) void patchify_kernel(const float* __restrict__ img,
                                                       unsigned short* __restrict__ patch)
{
    int idx = blockIdx.x * 256 + threadIdx.x;          // row*768 + e
    int e = idx % PELEMS, row = idx / PELEMS;
    int b = row / NPATCH, n = row % NPATCH;
    int kh = n / KW_, kw = n % KW_;
    int c = e >> 8, p = (e >> 4) & 15, q2 = e & 15;
    patch[idx] = f2bf(img[(((size_t)b * C_ + c) * H_ + kh * 16 + p) * W_ + kw * 16 + q2]);
}

__global__ __launch_bounds__(256) void build_x_kernel(const float* __restrict__ tok,
                                                      const int* __restrict__ flags,
                                                      const float* __restrict__ cls,
                                                      const float* __restrict__ mtok,
                                                      const float* __restrict__ pos,
                                                      float* __restrict__ x)
{
    int row = blockIdx.x;
    int b = row / NTOK, rr = row % NTOK;
    int tid = threadIdx.x;
#pragma unroll
    for (int i = 0; i < 3; ++i) {
        int d = tid + (i << 8);
        float v;
        if (rr == 0) v = cls[d];
        else {
            int n = rr - 1;
            v = flags[b * NPATCH + n] ? mtok[d]
                                      : tok[((size_t)b * NPATCH + n) * D_ + d];
        }
        x[(size_t)row * D_ + d] = v + pos[(size_t)rr * D_ + d];
    }
}

__global__ __launch_bounds__(256) void lnorm_kernel(const float* __restrict__ x,
                                                    unsigned short* __restrict__ g,
                                                    const float* __restrict__ gamma,
                                                    const float* __restrict__ delta)
{
    int row = blockIdx.x, tid = threadIdx.x;
    const float* xr = x + (size_t)row * D_;
    float v0 = xr[tid], v1 = xr[tid + 256], v2 = xr[tid + 512];

    __shared__ float red[256];
    red[tid] = v0 + v1 + v2;
    __syncthreads();
    for (int off = 128; off > 0; off >>= 1) {
        if (tid < off) red[tid] += red[tid + off];
        __syncthreads();
    }
    float mean = red[0] * (1.0f / D_);
    __syncthreads();
    float a0 = v0 - mean, a1 = v1 - mean, a2 = v2 - mean;
    red[tid] = a0 * a0 + a1 * a1 + a2 * a2;
    __syncthreads();
    for (int off = 128; off > 0; off >>= 1) {
        if (tid < off) red[tid] += red[tid + off];
        __syncthreads();
    }
    float var = red[0] * (1.0f / D_);
    float inv = gamma[0] / sqrtf(var + EPS_);
    unsigned short* gr = g + (size_t)row * D_;
    gr[tid]       = f2bf(a0 * inv + delta[tid]);
    gr[tid + 256] = f2bf(a1 * inv + delta[tid + 256]);
    gr[tid + 512] = f2bf(a2 * inv + delta[tid + 512]);
}

// ---------------------------------------------------------------------------
__global__ __launch_bounds__(256) void unpatch_kernel(const float* __restrict__ dec,
                                                      float* __restrict__ out)
{
    int idx = blockIdx.x * 256 + threadIdx.x;
    int ww = idx % W_;
    int t2 = idx / W_;
    int hh = t2 % H_;
    int t3 = t2 / H_;
    int c  = t3 % C_;
    int b  = t3 / C_;
    int kh = hh >> 4, p = hh & 15, kw = ww >> 4, q2 = ww & 15;
    int n = kh * KW_ + kw;
    int e = (c << 8) + (p << 4) + q2;
    out[idx] = dec[((size_t)b * NTOK + 1 + n) * D_ + e];
}

// ---------------------------------------------------------------------------
extern "C" void kernel_launch(void* const* d_in, const int* in_sizes, int n_in,
                              void* d_out, int out_size, void* d_ws, size_t ws_size,
                              hipStream_t stream)
{
    const float* img   = (const float*)d_in[0];
    const int*   mask  = (const int*)d_in[1];
    const float* enc_W = (const float*)d_in[2];
    const float* enc_b = (const float*)d_in[3];
    const float* dec_W = (const float*)d_in[4];
    const float* dec_b = (const float*)d_in[5];
    const float* cls   = (const float*)d_in[6];
    const float* mtok  = (const float*)d_in[7];
    const float* pos   = (const float*)d_in[8];
    const float* Wq    = (const float*)d_in[9];
    const float* Wk    = (const float*)d_in[10];
    const float* Xi    = (const float*)d_in[11];
    const float* gamma = (const float*)d_in[12];
    const float* delta = (const float*)d_in[13];
    float* out = (float*)d_out;

    float* ws = (float*)d_ws;
    size_t off = 0;
    auto alloc = [&](size_t nfloats) {
        off = (off + 63) & ~(size_t)63;
        float* p = ws + off; off += nfloats; return p;
    };
    float*          x    = alloc((size_t)MPAD * D_);                  // fp32
    unsigned short* g    = (unsigned short*)alloc((size_t)MPAD * D_ / 2);
    // qk bf16 [MPAD][1536]; bytes reused as dec fp32 [MPAD][768] at the end
    unsigned short* qkg  = (unsigned short*)alloc((size_t)MPAD * QKLD / 2);
    float*          decb = (float*)qkg;
    unsigned short* pack = (unsigned short*)alloc((size_t)MPAD * PACKLD / 2);
    unsigned short* Pg   = (unsigned short*)alloc((size_t)B_ * HEADS_ * NTOK * PGP / 2);
    unsigned short* W2   = (unsigned short*)alloc((size_t)W2LD * D_ / 2);
    unsigned short* Bpk  = (unsigned short*)alloc((size_t)D_ * PACKLD / 2);
    unsigned short* decT = (unsigned short*)alloc((size_t)D_ * D_ / 2);
    unsigned short* encT = (unsigned short*)alloc((size_t)D_ * D_ / 2);
    int*            flags = (int*)alloc(B_ * NPATCH);
    // setup-phase overlays inside pack (dead until first hid GEMM)
    unsigned short* patch = pack;                                // MPAD x 768 bf16
    float*          tok   = (float*)(pack + (size_t)MPAD * D_);  // MPAD x 768 fp32

    const dim3 blk(256);

    // ---- one-time packs ----
    w2pack_kernel<<<dim3(W2LD * D_ / 256), blk, 0, stream>>>(Wq, Wk, Xi, W2);
    bpack_kernel<<<dim3(D_ * PACKLD / 256), blk, 0, stream>>>(Xi, Wq, Wk, Bpk);
    t768_kernel<<<dim3(D_ * D_ / 256), blk, 0, stream>>>(dec_W, decT);
    t768_kernel<<<dim3(D_ * D_ / 256), blk, 0, stream>>>(enc_W, encT);
    mask_flags_kernel<<<dim3(1), dim3(64), 0, stream>>>(mask, flags);

    // ---- encode + build x ----
    patchify_kernel<<<dim3(B_ * NPATCH * PELEMS / 256), blk, 0, stream>>>(img, patch);
    mfma_gemm<0, false, true><<<dim3(D_ / 128, MPAD / 128), blk, 0, stream>>>(
        patch, PELEMS, encT, PELEMS, tok, D_, nullptr, enc_b, PELEMS);
    build_x_kernel<<<dim3(ROWS), blk, 0, stream>>>(tok, flags, cls, mtok, pos, x);

    // ---- energy-descent loop ----
    for (int step = 0; step < NSTEPS; ++step) {
        lnorm_kernel<<<dim3(ROWS), blk, 0, stream>>>(x, g, gamma, delta);
        // [qk | hid] = g @ [Wq|Wk|Xi]  (swizzled 1D grid, split epilogue)
        mfma_gemm<3, false, false><<<dim3(1024), blk, 0, stream>>>(
            g, D_, W2, D_, qkg, QKLD, pack, nullptr, D_);
        // attention: P + Gq (MFMA S), then Gk
        attn_pgq_kernel<<<dim3(B_ * HEADS_, 7), blk, 0, stream>>>(qkg, Pg, pack);
        attn_gk_kernel<<<dim3(B_ * HEADS_, 4), blk, 0, stream>>>(qkg, Pg, pack);
        // x += ALPHA * ([hid|Gq|Gk] @ [Xi|Wq|Wk]^T)  (split-K x4, atomic)
        mfma_gemm<4, false, false><<<dim3(D_ / 128, MPAD / 128, KSPLIT), blk, 0, stream>>>(
            pack, PACKLD, Bpk, PACKLD, x, D_, nullptr, nullptr, PACKLD / KSPLIT);
    }

    // ---- decode + unpatchify ----
    lnorm_kernel<<<dim3(ROWS), blk, 0, stream>>>(x, g, gamma, delta);
    mfma_gemm<0, false, true><<<dim3(D_ / 128, MPAD / 128), blk, 0, stream>>>(
        g, D_, decT, D_, decb, D_, nullptr, dec_b, D_);
    unpatch_kernel<<<dim3(B_ * C_ * H_ * W_ / 256), blk, 0, stream>>>(decb, out);
}

// Round 9
// 2847.641 us; speedup vs baseline: 1.5470x; 1.5470x over previous
//
#include <hip/hip_runtime.h>
#include <math.h>

// ---- problem constants ----
#define C_      3
#define H_      224
#define W_      224
#define KH_     14
#define KW_     14
#define NPATCH  196
#define PELEMS  768
#define D_      768
#define HEADS_  12
#define Y_      64
#define MHID    3072
#define NMASK   100
#define NSTEPS  12
#define ALPHA_  0.1f
#define BETA_   0.125f
#define EPS_    1e-5f
#define B_      16
#define NTOK    197
#define ROWS    (B_*NTOK)   /* 3152 real rows */
#define MPAD    3200        /* 25 * 128 */
#define QKLD    1536        /* fused q|k leading dim */
#define PACKLD  4608        /* hid(3072) | Gq(768) | Gk(768) */
#define W2LD    4608        /* qk(1536) | hid(3072) fused B rows */
#define PGP     208         /* global P pitch (bf16), 13*16 */
#define KSPLIT  8           /* grad GEMM split-K factor (4608/8=576=9*64) */

typedef short short8 __attribute__((ext_vector_type(8)));
typedef unsigned short ushort8 __attribute__((ext_vector_type(8)));
typedef float floatx4 __attribute__((ext_vector_type(4)));

__device__ __forceinline__ unsigned short f2bf(float f) {
    union { float f; unsigned u; } v; v.f = f;
    unsigned r = (v.u + 0x7FFFu + ((v.u >> 16) & 1u)) >> 16;
    return (unsigned short)r;
}
__device__ __forceinline__ float bf2f(unsigned short u) {
    union { unsigned u; float f; } v; v.u = ((unsigned)u) << 16;
    return v.f;
}

__device__ __forceinline__ void async_cp16(const void* g, void* l) {
    __builtin_amdgcn_global_load_lds(
        (const __attribute__((address_space(1))) unsigned int*)g,
        (__attribute__((address_space(3))) unsigned int*)l, 16, 0, 0);
}

// ---------------------------------------------------------------------------
// MFMA bf16 NT GEMM: C[M][N] = A(MxK bf16) @ B(NxK bf16)^T,  BK=64/iter,
// global_load_lds staging (round-7 proven structure; register-prefetch variant
// spilled to scratch — WRITE_SIZE 346 MB — do not reintroduce without a
// register-budget hint).
// OUT_MODE: 0 = fp32 store, 1 = bf16 store,
//           3 = split epilogue (col<1536 -> Cout bf16 ld QKLD, else relu ->
//               Cout2 bf16 ld PACKLD) with XCD-rectangle swizzle (1D grid 1024),
//           4 = split-K: koff = blockIdx.z*K, atomicAdd(Cout, ALPHA*v) fp32
template<int OUT_MODE, bool RELU, bool HAS_BIAS>
__global__ __launch_bounds__(256) void mfma_gemm(
    const unsigned short* __restrict__ A, int lda,
    const unsigned short* __restrict__ B, int ldb,
    void* __restrict__ Cout, int ldc, void* __restrict__ Cout2,
    const float* __restrict__ bias, int K)
{
    __shared__ alignas(16) unsigned short ldsA[2][128 * 32];
    __shared__ alignas(16) unsigned short ldsB[2][128 * 32];

    int bx, by, koff = 0;
    if (OUT_MODE == 3) {
        int lin = blockIdx.x;
        int xcd = lin & 7, s = lin >> 3;
        int rg = xcd >> 1, cg = xcd & 1;
        int rs = (rg == 0) ? 7 : 6;
        int rstart = (rg == 0) ? 0 : (6 * rg + 1);
        if (s >= rs * 18) return;
        by = rstart + s % rs;
        bx = cg * 18 + s / rs;
    } else {
        bx = blockIdx.x; by = blockIdx.y;
        if (OUT_MODE == 4) koff = blockIdx.z * K;
    }

    const int t    = threadIdx.x;
    const int wave = t >> 6;
    const int lane = t & 63;
    const int row0 = by << 7;
    const int col0 = bx << 7;
    const int wm = (wave & 1) << 6;
    const int wn = (wave >> 1) << 6;
    const int r  = lane & 15;
    const int qd = lane >> 4;

    const unsigned short* Abase = A + (size_t)row0 * lda + koff;
    const unsigned short* Bbase = B + (size_t)col0 * ldb + koff;

    floatx4 acc[4][4];
#pragma unroll
    for (int i = 0; i < 4; ++i)
#pragma unroll
        for (int j = 0; j < 4; ++j)
            acc[i][j] = (floatx4){0.f, 0.f, 0.f, 0.f};

    const int row_a0 = t >> 2,           off_a0 = (t & 3) << 3;
    const int row_a1 = (t + 256) >> 2,   off_a1 = (t & 3) << 3;

    for (int k0 = 0; k0 < K; k0 += 64) {
#pragma unroll
        for (int kb = 0; kb < 2; ++kb) {
            const int kk = k0 + kb * 32;
            async_cp16(Abase + (size_t)row_a0 * lda + kk + off_a0,
                       ldsA[kb] + (wave << 9));
            async_cp16(Abase + (size_t)row_a1 * lda + kk + off_a1,
                       ldsA[kb] + 2048 + (wave << 9));
            async_cp16(Bbase + (size_t)row_a0 * ldb + kk + off_a0,
                       ldsB[kb] + (wave << 9));
            async_cp16(Bbase + (size_t)row_a1 * ldb + kk + off_a1,
                       ldsB[kb] + 2048 + (wave << 9));
        }
        __syncthreads();
#pragma unroll
        for (int kb = 0; kb < 2; ++kb) {
            short8 af[4], bfr[4];
#pragma unroll
            for (int i = 0; i < 4; ++i) {
                af[i]  = *(const short8*)&ldsA[kb][(wm + (i << 4) + r) * 32 + (qd << 3)];
                bfr[i] = *(const short8*)&ldsB[kb][(wn + (i << 4) + r) * 32 + (qd << 3)];
            }
#pragma unroll
            for (int i = 0; i < 4; ++i)
#pragma unroll
                for (int j = 0; j < 4; ++j)
                    acc[i][j] = __builtin_amdgcn_mfma_f32_16x16x32_bf16(
                                    af[i], bfr[j], acc[i][j], 0, 0, 0);
        }
        __syncthreads();
    }

#pragma unroll
    for (int i = 0; i < 4; ++i) {
#pragma unroll
        for (int j = 0; j < 4; ++j) {
            int cc = col0 + wn + (j << 4) + r;
#pragma unroll
            for (int reg = 0; reg < 4; ++reg) {
                int rr = row0 + wm + (i << 4) + (qd << 2) + reg;
                float v = acc[i][j][reg];
                if (HAS_BIAS) v += bias[cc];
                if (RELU)     v = fmaxf(v, 0.f);
                if (OUT_MODE == 1)
                    ((unsigned short*)Cout)[(size_t)rr * ldc + cc] = f2bf(v);
                else if (OUT_MODE == 3) {
                    if (cc < QKLD)
                        ((unsigned short*)Cout)[(size_t)rr * QKLD + cc] = f2bf(v);
                    else
                        ((unsigned short*)Cout2)[(size_t)rr * PACKLD + (cc - QKLD)]
                            = f2bf(fmaxf(v, 0.f));
                } else if (OUT_MODE == 4)
                    atomicAdd(&((float*)Cout)[(size_t)rr * ldc + cc], ALPHA_ * v);
                else
                    ((float*)Cout)[(size_t)rr * ldc + cc] = v;
            }
        }
    }
}

// ---------------------------------------------------------------------------
// Attention A: per (bh, 32-q-row chunk): S = Q K^T via MFMA, softmax (beta in
// exp), P -> global bf16 (pitch 208, pad cols zero), Gq -> pack cols 3072+.
__global__ __launch_bounds__(256) void attn_pgq_kernel(
    const unsigned short* __restrict__ qk,   // bf16 [MPAD][1536]
    unsigned short* __restrict__ Pg,         // bf16 [192*197][208]
    unsigned short* __restrict__ pack)
{
    const int bh = blockIdx.x;
    const int h = bh % HEADS_, b = bh / HEADS_;
    const int n0 = blockIdx.y << 5;
    const int csz = (NTOK - n0 < 32) ? (NTOK - n0) : 32;
    const int t = threadIdx.x;
    const int lane = t & 63, wave = t >> 6;
    const int ln15 = lane & 15, quad = lane >> 4;

    __shared__ alignas(16) unsigned short KsS[208 * 72];  // K_h m-major
    __shared__ alignas(16) unsigned short QcS[32 * 72];   // Q chunk
    __shared__ alignas(16) float Pm[32 * 224];            // S/P fp32

    const size_t rowbase = (size_t)(b * NTOK) * QKLD;
    const int hoff = h * 64;

    for (int idx = t; idx < NTOK * 8; idx += 256) {
        int m = idx >> 3, c8 = idx & 7;
        *(uint4*)&KsS[m * 72 + c8 * 8] =
            *(const uint4*)&qk[rowbase + (size_t)m * QKLD + 768 + hoff + c8 * 8];
    }
    for (int idx = t; idx < 88; idx += 256) {
        int m = 197 + (idx >> 3), c8 = idx & 7;
        *(uint4*)&KsS[m * 72 + c8 * 8] = (uint4){0, 0, 0, 0};
    }
    for (int idx = t; idx < csz * 8; idx += 256) {
        int nn = idx >> 3, c8 = idx & 7;
        *(uint4*)&QcS[nn * 72 + c8 * 8] =
            *(const uint4*)&qk[rowbase + (size_t)(n0 + nn) * QKLD + hoff + c8 * 8];
    }
    __syncthreads();

    // ---- S = Q K^T via MFMA ----
    {
        short8 aq[2][2];
#pragma unroll
        for (int mt = 0; mt < 2; ++mt)
#pragma unroll
            for (int kb = 0; kb < 2; ++kb)
                aq[mt][kb] = *(const short8*)
                    &QcS[(mt * 16 + ln15) * 72 + kb * 32 + quad * 8];

        for (int nt = wave; nt < 13; nt += 4) {
            short8 b0 = *(const short8*)&KsS[(nt * 16 + ln15) * 72 + quad * 8];
            short8 b1 = *(const short8*)&KsS[(nt * 16 + ln15) * 72 + 32 + quad * 8];
            floatx4 s0 = (floatx4){0.f, 0.f, 0.f, 0.f};
            floatx4 s1 = (floatx4){0.f, 0.f, 0.f, 0.f};
            s0 = __builtin_amdgcn_mfma_f32_16x16x32_bf16(aq[0][0], b0, s0, 0, 0, 0);
            s0 = __builtin_amdgcn_mfma_f32_16x16x32_bf16(aq[0][1], b1, s0, 0, 0, 0);
            s1 = __builtin_amdgcn_mfma_f32_16x16x32_bf16(aq[1][0], b0, s1, 0, 0, 0);
            s1 = __builtin_amdgcn_mfma_f32_16x16x32_bf16(aq[1][1], b1, s1, 0, 0, 0);
#pragma unroll
            for (int reg = 0; reg < 4; ++reg) {
                Pm[(quad * 4 + reg) * 224 + nt * 16 + ln15]        = s0[reg];
                Pm[(16 + quad * 4 + reg) * 224 + nt * 16 + ln15]   = s1[reg];
            }
        }
    }
    __syncthreads();

    // ---- softmax rows (beta applied inside exp) ----
    for (int nn = wave; nn < csz; nn += 4) {
        float v0 = Pm[nn * 224 + lane];
        float v1 = (lane +  64 < NTOK) ? Pm[nn * 224 + lane +  64] : -1e30f;
        float v2 = (lane + 128 < NTOK) ? Pm[nn * 224 + lane + 128] : -1e30f;
        float v3 = (lane + 192 < NTOK) ? Pm[nn * 224 + lane + 192] : -1e30f;
        float mx = fmaxf(fmaxf(v0, v1), fmaxf(v2, v3));
#pragma unroll
        for (int o = 32; o > 0; o >>= 1) mx = fmaxf(mx, __shfl_xor(mx, o, 64));
        float e0 = __expf((v0 - mx) * BETA_);
        float e1 = (lane +  64 < NTOK) ? __expf((v1 - mx) * BETA_) : 0.f;
        float e2 = (lane + 128 < NTOK) ? __expf((v2 - mx) * BETA_) : 0.f;
        float e3 = (lane + 192 < NTOK) ? __expf((v3 - mx) * BETA_) : 0.f;
        float s = e0 + e1 + e2 + e3;
#pragma unroll
        for (int o = 32; o > 0; o >>= 1) s += __shfl_xor(s, o, 64);
        float inv = 1.0f / s;
        Pm[nn * 224 + lane] = e0 * inv;
        if (lane +  64 < NTOK) Pm[nn * 224 + lane +  64] = e1 * inv;
        if (lane + 128 < NTOK) Pm[nn * 224 + lane + 128] = e2 * inv;
        if (lane + 192 < NTOK) Pm[nn * 224 + lane + 192] = e3 * inv;
    }
    __syncthreads();

    // ---- write P (bf16, pad cols 197..207 = 0) ----
    if (t < PGP) {
        for (int nn = 0; nn < csz; ++nn) {
            unsigned short v = (t < NTOK) ? f2bf(Pm[nn * 224 + t]) : (unsigned short)0;
            Pg[((size_t)bh * NTOK + n0 + nn) * PGP + t] = v;
        }
    }

    // ---- Gq[n][y] = sum_m P[n][m] K[m][y] ----
    {
        const int y = lane;
        const int rbase2 = wave * 8;
        float gq[8] = {0.f, 0.f, 0.f, 0.f, 0.f, 0.f, 0.f, 0.f};
        for (int m0 = 0; m0 < 200; m0 += 4) {
            float kv0 = bf2f(KsS[(m0 + 0) * 72 + y]);
            float kv1 = bf2f(KsS[(m0 + 1) * 72 + y]);
            float kv2 = bf2f(KsS[(m0 + 2) * 72 + y]);
            float kv3 = bf2f(KsS[(m0 + 3) * 72 + y]);
#pragma unroll
            for (int i2 = 0; i2 < 8; ++i2) {
                const float4 pv = *(const float4*)&Pm[(rbase2 + i2) * 224 + m0];
                gq[i2] += pv.x * kv0 + pv.y * kv1 + pv.z * kv2 + pv.w * kv3;
            }
        }
#pragma unroll
        for (int i2 = 0; i2 < 8; ++i2) {
            int nn = rbase2 + i2;
            if (nn < csz)
                pack[(size_t)(b * NTOK + n0 + nn) * PACKLD + 3072 + hoff + y]
                    = f2bf(gq[i2]);
        }
    }
}

// ---------------------------------------------------------------------------
// Attention B: per (bh, 64-m chunk): Gk[m][y] = sum_n P[n][m] Q[n][y]
__global__ __launch_bounds__(256) void attn_gk_kernel(
    const unsigned short* __restrict__ qk,
    const unsigned short* __restrict__ Pg,
    unsigned short* __restrict__ pack)
{
    const int bh = blockIdx.x;
    const int h = bh % HEADS_, b = bh / HEADS_;
    const int m0 = blockIdx.y << 6;
    const int t = threadIdx.x;
    const int y = t & 63, mg = t >> 6;

    __shared__ alignas(16) unsigned short Qs[NTOK * 72];
    __shared__ alignas(16) unsigned short Ps[32 * 64];

    const size_t rowbase = (size_t)(b * NTOK) * QKLD;
    const int hoff = h * 64;
    for (int idx = t; idx < NTOK * 8; idx += 256) {
        int n = idx >> 3, c8 = idx & 7;
        *(uint4*)&Qs[n * 72 + c8 * 8] =
            *(const uint4*)&qk[rowbase + (size_t)n * QKLD + hoff + c8 * 8];
    }

    float gk[16] = {0.f, 0.f, 0.f, 0.f, 0.f, 0.f, 0.f, 0.f,
                    0.f, 0.f, 0.f, 0.f, 0.f, 0.f, 0.f, 0.f};

    for (int nc = 0; nc < NTOK; nc += 32) {
        int csz = (NTOK - nc < 32) ? (NTOK - nc) : 32;
        __syncthreads();
        for (int idx = t; idx < csz * 8; idx += 256) {
            int nn = idx >> 3, c8 = idx & 7;
            uint4 v = (uint4){0, 0, 0, 0};
            if (m0 + c8 * 8 < PGP)
                v = *(const uint4*)&Pg[((size_t)bh * NTOK + nc + nn) * PGP + m0 + c8 * 8];
            *(uint4*)&Ps[nn * 64 + c8 * 8] = v;
        }
        __syncthreads();
        for (int nn = 0; nn < csz; ++nn) {
            float qv = bf2f(Qs[(nc + nn) * 72 + y]);
            ushort8 p0 = *(const ushort8*)&Ps[nn * 64 + mg * 16];
            ushort8 p1 = *(const ushort8*)&Ps[nn * 64 + mg * 16 + 8];
#pragma unroll
            for (int j = 0; j < 8; ++j) gk[j]     += bf2f(p0[j]) * qv;
#pragma unroll
            for (int j = 0; j < 8; ++j) gk[8 + j] += bf2f(p1[j]) * qv;
        }
    }

#pragma unroll
    for (int j = 0; j < 16; ++j) {
        int m = m0 + mg * 16 + j;
        if (m < NTOK)
            pack[(size_t)(b * NTOK + m) * PACKLD + 3840 + hoff + y] = f2bf(gk[j]);
    }
}

// ---------------------------------------------------------------------------
// setup conversions
__global__ __launch_bounds__(256) void w2pack_kernel(const float* __restrict__ Wq,
                                                     const float* __restrict__ Wk,
                                                     const float* __restrict__ Xi,
                                                     unsigned short* __restrict__ out)
{
    int idx = blockIdx.x * 256 + threadIdx.x;          // n*768 + d
    int d = idx % D_, n = idx / D_;
    float v;
    if (n < 768)       v = Wq[((size_t)(n >> 6) * D_ + d) * Y_ + (n & 63)];
    else if (n < 1536) { int e = n - 768; v = Wk[((size_t)(e >> 6) * D_ + d) * Y_ + (e & 63)]; }
    else               v = Xi[(size_t)d * MHID + (n - 1536)];
    out[idx] = f2bf(v);
}

__global__ __launch_bounds__(256) void bpack_kernel(const float* __restrict__ Xi,
                                                    const float* __restrict__ Wq,
                                                    const float* __restrict__ Wk,
                                                    unsigned short* __restrict__ out)
{
    int idx = blockIdx.x * 256 + threadIdx.x;          // d*4608 + c
    int c = idx % PACKLD, d = idx / PACKLD;
    float v;
    if (c < 3072)       v = Xi[(size_t)d * MHID + c];
    else if (c < 3840)  { int e = c - 3072; v = Wq[((size_t)(e >> 6) * D_ + d) * Y_ + (e & 63)]; }
    else                { int e = c - 3840; v = Wk[((size_t)(e >> 6) * D_ + d) * Y_ + (e & 63)]; }
    out[idx] = f2bf(v);
}

__global__ __launch_bounds__(256) void t768_kernel(const float* __restrict__ in,
                                                   unsigned short* __restrict__ out)
{
    int idx = blockIdx.x * 256 + threadIdx.x;          // n*768 + k
    int k = idx % D_, n = idx / D_;
    out[idx] = f2bf(in[(size_t)k * D_ + n]);
}

// ---------------------------------------------------------------------------
__global__ void mask_flags_kernel(const int* __restrict__ mask, int* __restrict__ flags)
{
    int b = threadIdx.x;
    if (b >= B_) return;
    const int* mb = mask + b * NPATCH;
    int* fb = flags + b * NPATCH;
    int cnt = 0;
    for (int n = 0; n < NPATCH; ++n) {
        int mv = mb[n];
        fb[n] = (mv == 1 && cnt < NMASK) ? 1 : 0;
        cnt += (mv == 1);
    }
    if (cnt < NMASK) fb[0] = 1;
}

__global__ __launch_bounds__(256) void patchify_kernel(const float* __restrict__ img,
                                                       unsigned short* __restrict__ patch)
{
    int idx = blockIdx.x * 256 + threadIdx.x;          // row*768 + e
    int e = idx % PELEMS, row = idx / PELEMS;
    int b = row / NPATCH, n = row % NPATCH;
    int kh = n / KW_, kw = n % KW_;
    int c = e >> 8, p = (e >> 4) & 15, q2 = e & 15;
    patch[idx] = f2bf(img[(((size_t)b * C_ + c) * H_ + kh * 16 + p) * W_ + kw * 16 + q2]);
}

__global__ __launch_bounds__(256) void build_x_kernel(const float* __restrict__ tok,
                                                      const int* __restrict__ flags,
                                                      const float* __restrict__ cls,
                                                      const float* __restrict__ mtok,
                                                      const float* __restrict__ pos,
                                                      float* __restrict__ x)
{
    int row = blockIdx.x;
    int b = row / NTOK, rr = row % NTOK;
    int tid = threadIdx.x;
#pragma unroll
    for (int i = 0; i < 3; ++i) {
        int d = tid + (i << 8);
        float v;
        if (rr == 0) v = cls[d];
        else {
            int n = rr - 1;
            v = flags[b * NPATCH + n] ? mtok[d]
                                      : tok[((size_t)b * NPATCH + n) * D_ + d];
        }
        x[(size_t)row * D_ + d] = v + pos[(size_t)rr * D_ + d];
    }
}

__global__ __launch_bounds__(256) void lnorm_kernel(const float* __restrict__ x,
                                                    unsigned short* __restrict__ g,
                                                    const float* __restrict__ gamma,
                                                    const float* __restrict__ delta)
{
    int row = blockIdx.x, tid = threadIdx.x;
    const float* xr = x + (size_t)row * D_;
    float v0 = xr[tid], v1 = xr[tid + 256], v2 = xr[tid + 512];

    __shared__ float red[256];
    red[tid] = v0 + v1 + v2;
    __syncthreads();
    for (int off = 128; off > 0; off >>= 1) {
        if (tid < off) red[tid] += red[tid + off];
        __syncthreads();
    }
    float mean = red[0] * (1.0f / D_);
    __syncthreads();
    float a0 = v0 - mean, a1 = v1 - mean, a2 = v2 - mean;
    red[tid] = a0 * a0 + a1 * a1 + a2 * a2;
    __syncthreads();
    for (int off = 128; off > 0; off >>= 1) {
        if (tid < off) red[tid] += red[tid + off];
        __syncthreads();
    }
    float var = red[0] * (1.0f / D_);
    float inv = gamma[0] / sqrtf(var + EPS_);
    unsigned short* gr = g + (size_t)row * D_;
    gr[tid]       = f2bf(a0 * inv + delta[tid]);
    gr[tid + 256] = f2bf(a1 * inv + delta[tid + 256]);
    gr[tid + 512] = f2bf(a2 * inv + delta[tid + 512]);
}

// ---------------------------------------------------------------------------
__global__ __launch_bounds__(256) void unpatch_kernel(const float* __restrict__ dec,
                                                      float* __restrict__ out)
{
    int idx = blockIdx.x * 256 + threadIdx.x;
    int ww = idx % W_;
    int t2 = idx / W_;
    int hh = t2 % H_;
    int t3 = t2 / H_;
    int c  = t3 % C_;
    int b  = t3 / C_;
    int kh = hh >> 4, p = hh & 15, kw = ww >> 4, q2 = ww & 15;
    int n = kh * KW_ + kw;
    int e = (c << 8) + (p << 4) + q2;
    out[idx] = dec[((size_t)b * NTOK + 1 + n) * D_ + e];
}

// ---------------------------------------------------------------------------
extern "C" void kernel_launch(void* const* d_in, const int* in_sizes, int n_in,
                              void* d_out, int out_size, void* d_ws, size_t ws_size,
                              hipStream_t stream)
{
    const float* img   = (const float*)d_in[0];
    const int*   mask  = (const int*)d_in[1];
    const float* enc_W = (const float*)d_in[2];
    const float* enc_b = (const float*)d_in[3];
    const float* dec_W = (const float*)d_in[4];
    const float* dec_b = (const float*)d_in[5];
    const float* cls   = (const float*)d_in[6];
    const float* mtok  = (const float*)d_in[7];
    const float* pos   = (const float*)d_in[8];
    const float* Wq    = (const float*)d_in[9];
    const float* Wk    = (const float*)d_in[10];
    const float* Xi    = (const float*)d_in[11];
    const float* gamma = (const float*)d_in[12];
    const float* delta = (const float*)d_in[13];
    float* out = (float*)d_out;

    float* ws = (float*)d_ws;
    size_t off = 0;
    auto alloc = [&](size_t nfloats) {
        off = (off + 63) & ~(size_t)63;
        float* p = ws + off; off += nfloats; return p;
    };
    float*          x    = alloc((size_t)MPAD * D_);                  // fp32
    unsigned short* g    = (unsigned short*)alloc((size_t)MPAD * D_ / 2);
    // qk bf16 [MPAD][1536]; bytes reused as dec fp32 [MPAD][768] at the end
    unsigned short* qkg  = (unsigned short*)alloc((size_t)MPAD * QKLD / 2);
    float*          decb = (float*)qkg;
    unsigned short* pack = (unsigned short*)alloc((size_t)MPAD * PACKLD / 2);
    unsigned short* Pg   = (unsigned short*)alloc((size_t)B_ * HEADS_ * NTOK * PGP / 2);
    unsigned short* W2   = (unsigned short*)alloc((size_t)W2LD * D_ / 2);
    unsigned short* Bpk  = (unsigned short*)alloc((size_t)D_ * PACKLD / 2);
    unsigned short* decT = (unsigned short*)alloc((size_t)D_ * D_ / 2);
    unsigned short* encT = (unsigned short*)alloc((size_t)D_ * D_ / 2);
    int*            flags = (int*)alloc(B_ * NPATCH);
    // setup-phase overlays inside pack (dead until first hid GEMM)
    unsigned short* patch = pack;                                // MPAD x 768 bf16
    float*          tok   = (float*)(pack + (size_t)MPAD * D_);  // MPAD x 768 fp32

    const dim3 blk(256);

    // ---- one-time packs ----
    w2pack_kernel<<<dim3(W2LD * D_ / 256), blk, 0, stream>>>(Wq, Wk, Xi, W2);
    bpack_kernel<<<dim3(D_ * PACKLD / 256), blk, 0, stream>>>(Xi, Wq, Wk, Bpk);
    t768_kernel<<<dim3(D_ * D_ / 256), blk, 0, stream>>>(dec_W, decT);
    t768_kernel<<<dim3(D_ * D_ / 256), blk, 0, stream>>>(enc_W, encT);
    mask_flags_kernel<<<dim3(1), dim3(64), 0, stream>>>(mask, flags);

    // ---- encode + build x ----
    patchify_kernel<<<dim3(B_ * NPATCH * PELEMS / 256), blk, 0, stream>>>(img, patch);
    mfma_gemm<0, false, true><<<dim3(D_ / 128, MPAD / 128), blk, 0, stream>>>(
        patch, PELEMS, encT, PELEMS, tok, D_, nullptr, enc_b, PELEMS);
    build_x_kernel<<<dim3(ROWS), blk, 0, stream>>>(tok, flags, cls, mtok, pos, x);

    // ---- energy-descent loop ----
    for (int step = 0; step < NSTEPS; ++step) {
        lnorm_kernel<<<dim3(ROWS), blk, 0, stream>>>(x, g, gamma, delta);
        // [qk | hid] = g @ [Wq|Wk|Xi]  (swizzled 1D grid, split epilogue)
        mfma_gemm<3, false, false><<<dim3(1024), blk, 0, stream>>>(
            g, D_, W2, D_, qkg, QKLD, pack, nullptr, D_);
        // attention: P + Gq (MFMA S), then Gk
        attn_pgq_kernel<<<dim3(B_ * HEADS_, 7), blk, 0, stream>>>(qkg, Pg, pack);
        attn_gk_kernel<<<dim3(B_ * HEADS_, 4), blk, 0, stream>>>(qkg, Pg, pack);
        // x += ALPHA * ([hid|Gq|Gk] @ [Xi|Wq|Wk]^T)  (split-K x8, atomic)
        mfma_gemm<4, false, false><<<dim3(D_ / 128, MPAD / 128, KSPLIT), blk, 0, stream>>>(
            pack, PACKLD, Bpk, PACKLD, x, D_, nullptr, nullptr, PACKLD / KSPLIT);
    }

    // ---- decode + unpatchify ----
    lnorm_kernel<<<dim3(ROWS), blk, 0, stream>>>(x, g, gamma, delta);
    mfma_gemm<0, false, true><<<dim3(D_ / 128, MPAD / 128), blk, 0, stream>>>(
        g, D_, decT, D_, decb, D_, nullptr, dec_b, D_);
    unpatch_kernel<<<dim3(B_ * C_ * H_ * W_ / 256), blk, 0, stream>>>(decb, out);
}

// Round 10
// 2517.580 us; speedup vs baseline: 1.7498x; 1.1311x over previous
//
#include <hip/hip_runtime.h>
#include <math.h>

// ---- problem constants ----
#define C_      3
#define H_      224
#define W_      224
#define KH_     14
#define KW_     14
#define NPATCH  196
#define PELEMS  768
#define D_      768
#define HEADS_  12
#define Y_      64
#define MHID    3072
#define NMASK   100
#define NSTEPS  12
#define ALPHA_  0.1f
#define BETA_   0.125f
#define EPS_    1e-5f
#define B_      16
#define NTOK    197
#define ROWS    (B_*NTOK)   /* 3152 real rows */
#define MPAD    3200        /* 50 * 64 */
#define QKLD    1536        /* fused q|k leading dim */
#define PACKLD  4608        /* hid(3072) | Gq(768) | Gk(768) */
#define W2LD    4608        /* qk(1536) | hid(3072) fused B rows */
#define PGP     208         /* global P pitch (bf16), 13*16 */
#define KSPLIT  4           /* grad GEMM split-K (4608/4=1152=18*64) */

typedef short short8 __attribute__((ext_vector_type(8)));
typedef unsigned short ushort8 __attribute__((ext_vector_type(8)));
typedef float floatx4 __attribute__((ext_vector_type(4)));

__device__ __forceinline__ unsigned short f2bf(float f) {
    union { float f; unsigned u; } v; v.f = f;
    unsigned r = (v.u + 0x7FFFu + ((v.u >> 16) & 1u)) >> 16;
    return (unsigned short)r;
}
__device__ __forceinline__ float bf2f(unsigned short u) {
    union { unsigned u; float f; } v; v.u = ((unsigned)u) << 16;
    return v.f;
}

__device__ __forceinline__ void async_cp16(const void* g, void* l) {
    __builtin_amdgcn_global_load_lds(
        (const __attribute__((address_space(1))) unsigned int*)g,
        (__attribute__((address_space(3))) unsigned int*)l, 16, 0, 0);
}

// ---------------------------------------------------------------------------
// MFMA bf16 NT GEMM: C[M][N] = A(MxK bf16) @ B(NxK bf16)^T.
// 64x128 tile, BK=64/iter, global_load_lds staging. Small M-tile chosen for
// grid size: 128x128 left the GEMMs at 3.5 blocks/CU, latency-bound (r7-r9).
// (Register-prefetch staging spills to scratch on this compiler — r8, 346 MB
// WRITE — keep global_load_lds.)
// OUT_MODE: 0 = fp32 store, 1 = bf16 store,
//           3 = split epilogue: col<1536 -> Cout bf16 (ld QKLD), else relu ->
//               Cout2 bf16 (ld PACKLD, col-1536)
//           4 = split-K: koff = blockIdx.z*K, atomicAdd(Cout, ALPHA*v) fp32
template<int OUT_MODE, bool RELU, bool HAS_BIAS>
__global__ __launch_bounds__(256) void mfma_gemm(
    const unsigned short* __restrict__ A, int lda,
    const unsigned short* __restrict__ B, int ldb,
    void* __restrict__ Cout, int ldc, void* __restrict__ Cout2,
    const float* __restrict__ bias, int K)
{
    __shared__ alignas(16) unsigned short ldsA[2][64 * 32];
    __shared__ alignas(16) unsigned short ldsB[2][128 * 32];

    const int bx = blockIdx.x, by = blockIdx.y;
    const int koff = (OUT_MODE == 4) ? blockIdx.z * K : 0;

    const int t    = threadIdx.x;
    const int wave = t >> 6;
    const int lane = t & 63;
    const int row0 = by << 6;
    const int col0 = bx << 7;
    const int wm = (wave & 1) << 5;     // 0 / 32
    const int wn = (wave >> 1) << 6;    // 0 / 64
    const int r  = lane & 15;
    const int qd = lane >> 4;

    const unsigned short* Abase = A + (size_t)row0 * lda + koff;
    const unsigned short* Bbase = B + (size_t)col0 * ldb + koff;

    floatx4 acc[2][4];
#pragma unroll
    for (int i = 0; i < 2; ++i)
#pragma unroll
        for (int j = 0; j < 4; ++j)
            acc[i][j] = (floatx4){0.f, 0.f, 0.f, 0.f};

    // chunk decomposition: per 32-K buffer, rows of 32 shorts (64 B = 4 chunks)
    const int crow = t >> 2;            // 0..63
    const int coff = (t & 3) << 3;      // {0,8,16,24} shorts
    for (int k0 = 0; k0 < K; k0 += 64) {
#pragma unroll
        for (int kb = 0; kb < 2; ++kb) {
            const int kk = k0 + kb * 32;
            // A: 64 rows = 256 chunks = 1/thread
            async_cp16(Abase + (size_t)crow * lda + kk + coff,
                       ldsA[kb] + (wave << 9));
            // B: 128 rows = 512 chunks = 2/thread
            async_cp16(Bbase + (size_t)crow * ldb + kk + coff,
                       ldsB[kb] + (wave << 9));
            async_cp16(Bbase + (size_t)(64 + crow) * ldb + kk + coff,
                       ldsB[kb] + 2048 + (wave << 9));
        }
        __syncthreads();
#pragma unroll
        for (int kb = 0; kb < 2; ++kb) {
            short8 af[2], bfr[4];
#pragma unroll
            for (int i = 0; i < 2; ++i)
                af[i]  = *(const short8*)&ldsA[kb][(wm + (i << 4) + r) * 32 + (qd << 3)];
#pragma unroll
            for (int j = 0; j < 4; ++j)
                bfr[j] = *(const short8*)&ldsB[kb][(wn + (j << 4) + r) * 32 + (qd << 3)];
#pragma unroll
            for (int i = 0; i < 2; ++i)
#pragma unroll
                for (int j = 0; j < 4; ++j)
                    acc[i][j] = __builtin_amdgcn_mfma_f32_16x16x32_bf16(
                                    af[i], bfr[j], acc[i][j], 0, 0, 0);
        }
        __syncthreads();
    }

#pragma unroll
    for (int i = 0; i < 2; ++i) {
#pragma unroll
        for (int j = 0; j < 4; ++j) {
            int cc = col0 + wn + (j << 4) + r;
#pragma unroll
            for (int reg = 0; reg < 4; ++reg) {
                int rr = row0 + wm + (i << 4) + (qd << 2) + reg;
                float v = acc[i][j][reg];
                if (HAS_BIAS) v += bias[cc];
                if (RELU)     v = fmaxf(v, 0.f);
                if (OUT_MODE == 1)
                    ((unsigned short*)Cout)[(size_t)rr * ldc + cc] = f2bf(v);
                else if (OUT_MODE == 3) {
                    if (cc < QKLD)
                        ((unsigned short*)Cout)[(size_t)rr * QKLD + cc] = f2bf(v);
                    else
                        ((unsigned short*)Cout2)[(size_t)rr * PACKLD + (cc - QKLD)]
                            = f2bf(fmaxf(v, 0.f));
                } else if (OUT_MODE == 4)
                    atomicAdd(&((float*)Cout)[(size_t)rr * ldc + cc], ALPHA_ * v);
                else
                    ((float*)Cout)[(size_t)rr * ldc + cc] = v;
            }
        }
    }
}

// ---------------------------------------------------------------------------
// Attention A: per (bh, 32-q-row chunk): S = Q K^T via MFMA, softmax (beta in
// exp), P -> global bf16 (pitch 208, pad cols zero), Gq -> pack cols 3072+.
__global__ __launch_bounds__(256) void attn_pgq_kernel(
    const unsigned short* __restrict__ qk,   // bf16 [MPAD][1536]
    unsigned short* __restrict__ Pg,         // bf16 [192*197][208]
    unsigned short* __restrict__ pack)
{
    const int bh = blockIdx.x;
    const int h = bh % HEADS_, b = bh / HEADS_;
    const int n0 = blockIdx.y << 5;
    const int csz = (NTOK - n0 < 32) ? (NTOK - n0) : 32;
    const int t = threadIdx.x;
    const int lane = t & 63, wave = t >> 6;
    const int ln15 = lane & 15, quad = lane >> 4;

    __shared__ alignas(16) unsigned short KsS[208 * 72];  // K_h m-major
    __shared__ alignas(16) unsigned short QcS[32 * 72];   // Q chunk
    __shared__ alignas(16) float Pm[32 * 224];            // S/P fp32

    const size_t rowbase = (size_t)(b * NTOK) * QKLD;
    const int hoff = h * 64;

    for (int idx = t; idx < NTOK * 8; idx += 256) {
        int m = idx >> 3, c8 = idx & 7;
        *(uint4*)&KsS[m * 72 + c8 * 8] =
            *(const uint4*)&qk[rowbase + (size_t)m * QKLD + 768 + hoff + c8 * 8];
    }
    for (int idx = t; idx < 88; idx += 256) {
        int m = 197 + (idx >> 3), c8 = idx & 7;
        *(uint4*)&KsS[m * 72 + c8 * 8] = (uint4){0, 0, 0, 0};
    }
    for (int idx = t; idx < csz * 8; idx += 256) {
        int nn = idx >> 3, c8 = idx & 7;
        *(uint4*)&QcS[nn * 72 + c8 * 8] =
            *(const uint4*)&qk[rowbase + (size_t)(n0 + nn) * QKLD + hoff + c8 * 8];
    }
    __syncthreads();

    // ---- S = Q K^T via MFMA ----
    {
        short8 aq[2][2];
#pragma unroll
        for (int mt = 0; mt < 2; ++mt)
#pragma unroll
            for (int kb = 0; kb < 2; ++kb)
                aq[mt][kb] = *(const short8*)
                    &QcS[(mt * 16 + ln15) * 72 + kb * 32 + quad * 8];

        for (int nt = wave; nt < 13; nt += 4) {
            short8 b0 = *(const short8*)&KsS[(nt * 16 + ln15) * 72 + quad * 8];
            short8 b1 = *(const short8*)&KsS[(nt * 16 + ln15) * 72 + 32 + quad * 8];
            floatx4 s0 = (floatx4){0.f, 0.f, 0.f, 0.f};
            floatx4 s1 = (floatx4){0.f, 0.f, 0.f, 0.f};
            s0 = __builtin_amdgcn_mfma_f32_16x16x32_bf16(aq[0][0], b0, s0, 0, 0, 0);
            s0 = __builtin_amdgcn_mfma_f32_16x16x32_bf16(aq[0][1], b1, s0, 0, 0, 0);
            s1 = __builtin_amdgcn_mfma_f32_16x16x32_bf16(aq[1][0], b0, s1, 0, 0, 0);
            s1 = __builtin_amdgcn_mfma_f32_16x16x32_bf16(aq[1][1], b1, s1, 0, 0, 0);
#pragma unroll
            for (int reg = 0; reg < 4; ++reg) {
                Pm[(quad * 4 + reg) * 224 + nt * 16 + ln15]        = s0[reg];
                Pm[(16 + quad * 4 + reg) * 224 + nt * 16 + ln15]   = s1[reg];
            }
        }
    }
    __syncthreads();

    // ---- softmax rows (beta applied inside exp) ----
    for (int nn = wave; nn < csz; nn += 4) {
        float v0 = Pm[nn * 224 + lane];
        float v1 = (lane +  64 < NTOK) ? Pm[nn * 224 + lane +  64] : -1e30f;
        float v2 = (lane + 128 < NTOK) ? Pm[nn * 224 + lane + 128] : -1e30f;
        float v3 = (lane + 192 < NTOK) ? Pm[nn * 224 + lane + 192] : -1e30f;
        float mx = fmaxf(fmaxf(v0, v1), fmaxf(v2, v3));
#pragma unroll
        for (int o = 32; o > 0; o >>= 1) mx = fmaxf(mx, __shfl_xor(mx, o, 64));
        float e0 = __expf((v0 - mx) * BETA_);
        float e1 = (lane +  64 < NTOK) ? __expf((v1 - mx) * BETA_) : 0.f;
        float e2 = (lane + 128 < NTOK) ? __expf((v2 - mx) * BETA_) : 0.f;
        float e3 = (lane + 192 < NTOK) ? __expf((v3 - mx) * BETA_) : 0.f;
        float s = e0 + e1 + e2 + e3;
#pragma unroll
        for (int o = 32; o > 0; o >>= 1) s += __shfl_xor(s, o, 64);
        float inv = 1.0f / s;
        Pm[nn * 224 + lane] = e0 * inv;
        if (lane +  64 < NTOK) Pm[nn * 224 + lane +  64] = e1 * inv;
        if (lane + 128 < NTOK) Pm[nn * 224 + lane + 128] = e2 * inv;
        if (lane + 192 < NTOK) Pm[nn * 224 + lane + 192] = e3 * inv;
    }
    __syncthreads();

    // ---- write P (bf16, pad cols 197..207 = 0) ----
    if (t < PGP) {
        for (int nn = 0; nn < csz; ++nn) {
            unsigned short v = (t < NTOK) ? f2bf(Pm[nn * 224 + t]) : (unsigned short)0;
            Pg[((size_t)bh * NTOK + n0 + nn) * PGP + t] = v;
        }
    }

    // ---- Gq[n][y] = sum_m P[n][m] K[m][y] ----
    {
        const int y = lane;
        const int rbase2 = wave * 8;
        float gq[8] = {0.f, 0.f, 0.f, 0.f, 0.f, 0.f, 0.f, 0.f};
        for (int m0 = 0; m0 < 200; m0 += 4) {
            float kv0 = bf2f(KsS[(m0 + 0) * 72 + y]);
            float kv1 = bf2f(KsS[(m0 + 1) * 72 + y]);
            float kv2 = bf2f(KsS[(m0 + 2) * 72 + y]);
            float kv3 = bf2f(KsS[(m0 + 3) * 72 + y]);
#pragma unroll
            for (int i2 = 0; i2 < 8; ++i2) {
                const float4 pv = *(const float4*)&Pm[(rbase2 + i2) * 224 + m0];
                gq[i2] += pv.x * kv0 + pv.y * kv1 + pv.z * kv2 + pv.w * kv3;
            }
        }
#pragma unroll
        for (int i2 = 0; i2 < 8; ++i2) {
            int nn = rbase2 + i2;
            if (nn < csz)
                pack[(size_t)(b * NTOK + n0 + nn) * PACKLD + 3072 + hoff + y]
                    = f2bf(gq[i2]);
        }
    }
}

// ---------------------------------------------------------------------------
// Attention B: per (bh, 64-m chunk): Gk[m][y] = sum_n P[n][m] Q[n][y]
__global__ __launch_bounds__(256) void attn_gk_kernel(
    const unsigned short* __restrict__ qk,
    const unsigned short* __restrict__ Pg,
    unsigned short* __restrict__ pack)
{
    const int bh = blockIdx.x;
    const int h = bh % HEADS_, b = bh / HEADS_;
    const int m0 = blockIdx.y << 6;
    const int t = threadIdx.x;
    const int y = t & 63, mg = t >> 6;

    __shared__ alignas(16) unsigned short Qs[NTOK * 72];
    __shared__ alignas(16) unsigned short Ps[32 * 64];

    const size_t rowbase = (size_t)(b * NTOK) * QKLD;
    const int hoff = h * 64;
    for (int idx = t; idx < NTOK * 8; idx += 256) {
        int n = idx >> 3, c8 = idx & 7;
        *(uint4*)&Qs[n * 72 + c8 * 8] =
            *(const uint4*)&qk[rowbase + (size_t)n * QKLD + hoff + c8 * 8];
    }

    float gk[16] = {0.f, 0.f, 0.f, 0.f, 0.f, 0.f, 0.f, 0.f,
                    0.f, 0.f, 0.f, 0.f, 0.f, 0.f, 0.f, 0.f};

    for (int nc = 0; nc < NTOK; nc += 32) {
        int csz = (NTOK - nc < 32) ? (NTOK - nc) : 32;
        __syncthreads();
        for (int idx = t; idx < csz * 8; idx += 256) {
            int nn = idx >> 3, c8 = idx & 7;
            uint4 v = (uint4){0, 0, 0, 0};
            if (m0 + c8 * 8 < PGP)
                v = *(const uint4*)&Pg[((size_t)bh * NTOK + nc + nn) * PGP + m0 + c8 * 8];
            *(uint4*)&Ps[nn * 64 + c8 * 8] = v;
        }
        __syncthreads();
        for (int nn = 0; nn < csz; ++nn) {
            float qv = bf2f(Qs[(nc + nn) * 72 + y]);
            ushort8 p0 = *(const ushort8*)&Ps[nn * 64 + mg * 16];
            ushort8 p1 = *(const ushort8*)&Ps[nn * 64 + mg * 16 + 8];
#pragma unroll
            for (int j = 0; j < 8; ++j) gk[j]     += bf2f(p0[j]) * qv;
#pragma unroll
            for (int j = 0; j < 8; ++j) gk[8 + j] += bf2f(p1[j]) * qv;
        }
    }

#pragma unroll
    for (int j = 0; j < 16; ++j) {
        int m = m0 + mg * 16 + j;
        if (m < NTOK)
            pack[(size_t)(b * NTOK + m) * PACKLD + 3840 + hoff + y] = f2bf(gk[j]);
    }
}

// ---------------------------------------------------------------------------
// setup conversions
__global__ __launch_bounds__(256) void w2pack_kernel(const float* __restrict__ Wq,
                                                     const float* __restrict__ Wk,
                                                     const float* __restrict__ Xi,
                                                     unsigned short* __restrict__ out)
{
    int idx = blockIdx.x * 256 + threadIdx.x;          // n*768 + d
    int d = idx % D_, n = idx / D_;
    float v;
    if (n < 768)       v = Wq[((size_t)(n >> 6) * D_ + d) * Y_ + (n & 63)];
    else if (n < 1536) { int e = n - 768; v = Wk[((size_t)(e >> 6) * D_ + d) * Y_ + (e & 63)]; }
    else               v = Xi[(size_t)d * MHID + (n - 1536)];
    out[idx] = f2bf(v);
}

__global__ __launch_bounds__(256) void bpack_kernel(const float* __restrict__ Xi,
                                                    const float* __restrict__ Wq,
                                                    const float* __restrict__ Wk,
                                                    unsigned short* __restrict__ out)
{
    int idx = blockIdx.x * 256 + threadIdx.x;          // d*4608 + c
    int c = idx % PACKLD, d = idx / PACKLD;
    float v;
    if (c < 3072)       v = Xi[(size_t)d * MHID + c];
    else if (c < 3840)  { int e = c - 3072; v = Wq[((size_t)(e >> 6) * D_ + d) * Y_ + (e & 63)]; }
    else                { int e = c - 3840; v = Wk[((size_t)(e >> 6) * D_ + d) * Y_ + (e & 63)]; }
    out[idx] = f2bf(v);
}

__global__ __launch_bounds__(256) void t768_kernel(const float* __restrict__ in,
                                                   unsigned short* __restrict__ out)
{
    int idx = blockIdx.x * 256 + threadIdx.x;          // n*768 + k
    int k = idx % D_, n = idx / D_;
    out[idx] = f2bf(in[(size_t)k * D_ + n]);
}

// ---------------------------------------------------------------------------
__global__ void mask_flags_kernel(const int* __restrict__ mask, int* __restrict__ flags)
{
    int b = threadIdx.x;
    if (b >= B_) return;
    const int* mb = mask + b * NPATCH;
    int* fb = flags + b * NPATCH;
    int cnt = 0;
    for (int n = 0; n < NPATCH; ++n) {
        int mv = mb[n];
        fb[n] = (mv == 1 && cnt < NMASK) ? 1 : 0;
        cnt += (mv == 1);
    }
    if (cnt < NMASK) fb[0] = 1;
}

__global__ __launch_bounds__(256) void patchify_kernel(const float* __restrict__ img,
                                                       unsigned short* __restrict__ patch)
{
    int idx = blockIdx.x * 256 + threadIdx.x;          // row*768 + e
    int e = idx % PELEMS, row = idx / PELEMS;
    int b = row / NPATCH, n = row % NPATCH;
    int kh = n / KW_, kw = n % KW_;
    int c = e >> 8, p = (e >> 4) & 15, q2 = e & 15;
    patch[idx] = f2bf(img[(((size_t)b * C_ + c) * H_ + kh * 16 + p) * W_ + kw * 16 + q2]);
}

__global__ __launch_bounds__(256) void build_x_kernel(const float* __restrict__ tok,
                                                      const int* __restrict__ flags,
                                                      const float* __restrict__ cls,
                                                      const float* __restrict__ mtok,
                                                      const float* __restrict__ pos,
                                                      float* __restrict__ x)
{
    int row = blockIdx.x;
    int b = row / NTOK, rr = row % NTOK;
    int tid = threadIdx.x;
#pragma unroll
    for (int i = 0; i < 3; ++i) {
        int d = tid + (i << 8);
        float v;
        if (rr == 0) v = cls[d];
        else {
            int n = rr - 1;
            v = flags[b * NPATCH + n] ? mtok[d]
                                      : tok[((size_t)b * NPATCH + n) * D_ + d];
        }
        x[(size_t)row * D_ + d] = v + pos[(size_t)rr * D_ + d];
    }
}

__global__ __launch_bounds__(256) void lnorm_kernel(const float* __restrict__ x,
                                                    unsigned short* __restrict__ g,
                                                    const float* __restrict__ gamma,
                                                    const float* __restrict__ delta)
{
    int row = blockIdx.x, tid = threadIdx.x;
    const float* xr = x + (size_t)row * D_;
    float v0 = xr[tid], v1 = xr[tid + 256], v2 = xr[tid + 512];

    __shared__ float red[256];
    red[tid] = v0 + v1 + v2;
    __syncthreads();
    for (int off = 128; off > 0; off >>= 1) {
        if (tid < off) red[tid] += red[tid + off];
        __syncthreads();
    }
    float mean = red[0] * (1.0f / D_);
    __syncthreads();
    float a0 = v0 - mean, a1 = v1 - mean, a2 = v2 - mean;
    red[tid] = a0 * a0 + a1 * a1 + a2 * a2;
    __syncthreads();
    for (int off = 128; off > 0; off >>= 1) {
        if (tid < off) red[tid] += red[tid + off];
        __syncthreads();
    }
    float var = red[0] * (1.0f / D_);
    float inv = gamma[0] / sqrtf(var + EPS_);
    unsigned short* gr = g + (size_t)row * D_;
    gr[tid]       = f2bf(a0 * inv + delta[tid]);
    gr[tid + 256] = f2bf(a1 * inv + delta[tid + 256]);
    gr[tid + 512] = f2bf(a2 * inv + delta[tid + 512]);
}

// ---------------------------------------------------------------------------
__global__ __launch_bounds__(256) void unpatch_kernel(const float* __restrict__ dec,
                                                      float* __restrict__ out)
{
    int idx = blockIdx.x * 256 + threadIdx.x;
    int ww = idx % W_;
    int t2 = idx / W_;
    int hh = t2 % H_;
    int t3 = t2 / H_;
    int c  = t3 % C_;
    int b  = t3 / C_;
    int kh = hh >> 4, p = hh & 15, kw = ww >> 4, q2 = ww & 15;
    int n = kh * KW_ + kw;
    int e = (c << 8) + (p << 4) + q2;
    out[idx] = dec[((size_t)b * NTOK + 1 + n) * D_ + e];
}

// ---------------------------------------------------------------------------
extern "C" void kernel_launch(void* const* d_in, const int* in_sizes, int n_in,
                              void* d_out, int out_size, void* d_ws, size_t ws_size,
                              hipStream_t stream)
{
    const float* img   = (const float*)d_in[0];
    const int*   mask  = (const int*)d_in[1];
    const float* enc_W = (const float*)d_in[2];
    const float* enc_b = (const float*)d_in[3];
    const float* dec_W = (const float*)d_in[4];
    const float* dec_b = (const float*)d_in[5];
    const float* cls   = (const float*)d_in[6];
    const float* mtok  = (const float*)d_in[7];
    const float* pos   = (const float*)d_in[8];
    const float* Wq    = (const float*)d_in[9];
    const float* Wk    = (const float*)d_in[10];
    const float* Xi    = (const float*)d_in[11];
    const float* gamma = (const float*)d_in[12];
    const float* delta = (const float*)d_in[13];
    float* out = (float*)d_out;

    float* ws = (float*)d_ws;
    size_t off = 0;
    auto alloc = [&](size_t nfloats) {
        off = (off + 63) & ~(size_t)63;
        float* p = ws + off; off += nfloats; return p;
    };
    float*          x    = alloc((size_t)MPAD * D_);                  // fp32
    unsigned short* g    = (unsigned short*)alloc((size_t)MPAD * D_ / 2);
    // qk bf16 [MPAD][1536]; bytes reused as dec fp32 [MPAD][768] at the end
    unsigned short* qkg  = (unsigned short*)alloc((size_t)MPAD * QKLD / 2);
    float*          decb = (float*)qkg;
    unsigned short* pack = (unsigned short*)alloc((size_t)MPAD * PACKLD / 2);
    unsigned short* Pg   = (unsigned short*)alloc((size_t)B_ * HEADS_ * NTOK * PGP / 2);
    unsigned short* W2   = (unsigned short*)alloc((size_t)W2LD * D_ / 2);
    unsigned short* Bpk  = (unsigned short*)alloc((size_t)D_ * PACKLD / 2);
    unsigned short* decT = (unsigned short*)alloc((size_t)D_ * D_ / 2);
    unsigned short* encT = (unsigned short*)alloc((size_t)D_ * D_ / 2);
    int*            flags = (int*)alloc(B_ * NPATCH);
    // setup-phase overlays inside pack (dead until first hid GEMM)
    unsigned short* patch = pack;                                // MPAD x 768 bf16
    float*          tok   = (float*)(pack + (size_t)MPAD * D_);  // MPAD x 768 fp32

    const dim3 blk(256);

    // ---- one-time packs ----
    w2pack_kernel<<<dim3(W2LD * D_ / 256), blk, 0, stream>>>(Wq, Wk, Xi, W2);
    bpack_kernel<<<dim3(D_ * PACKLD / 256), blk, 0, stream>>>(Xi, Wq, Wk, Bpk);
    t768_kernel<<<dim3(D_ * D_ / 256), blk, 0, stream>>>(dec_W, decT);
    t768_kernel<<<dim3(D_ * D_ / 256), blk, 0, stream>>>(enc_W, encT);
    mask_flags_kernel<<<dim3(1), dim3(64), 0, stream>>>(mask, flags);

    // ---- encode + build x ----
    patchify_kernel<<<dim3(B_ * NPATCH * PELEMS / 256), blk, 0, stream>>>(img, patch);
    mfma_gemm<0, false, true><<<dim3(D_ / 128, MPAD / 64), blk, 0, stream>>>(
        patch, PELEMS, encT, PELEMS, tok, D_, nullptr, enc_b, PELEMS);
    build_x_kernel<<<dim3(ROWS), blk, 0, stream>>>(tok, flags, cls, mtok, pos, x);

    // ---- energy-descent loop ----
    for (int step = 0; step < NSTEPS; ++step) {
        lnorm_kernel<<<dim3(ROWS), blk, 0, stream>>>(x, g, gamma, delta);
        // [qk | hid] = g @ [Wq|Wk|Xi]  (split epilogue)
        mfma_gemm<3, false, false><<<dim3(W2LD / 128, MPAD / 64), blk, 0, stream>>>(
            g, D_, W2, D_, qkg, QKLD, pack, nullptr, D_);
        // attention: P + Gq (MFMA S), then Gk
        attn_pgq_kernel<<<dim3(B_ * HEADS_, 7), blk, 0, stream>>>(qkg, Pg, pack);
        attn_gk_kernel<<<dim3(B_ * HEADS_, 4), blk, 0, stream>>>(qkg, Pg, pack);
        // x += ALPHA * ([hid|Gq|Gk] @ [Xi|Wq|Wk]^T)  (split-K x4, atomic)
        mfma_gemm<4, false, false><<<dim3(D_ / 128, MPAD / 64, KSPLIT), blk, 0, stream>>>(
            pack, PACKLD, Bpk, PACKLD, x, D_, nullptr, nullptr, PACKLD / KSPLIT);
    }

    // ---- decode + unpatchify ----
    lnorm_kernel<<<dim3(ROWS), blk, 0, stream>>>(x, g, gamma, delta);
    mfma_gemm<0, false, true><<<dim3(D_ / 128, MPAD / 64), blk, 0, stream>>>(
        g, D_, decT, D_, decb, D_, nullptr, dec_b, D_);
    unpatch_kernel<<<dim3(B_ * C_ * H_ * W_ / 256), blk, 0, stream>>>(decb, out);
}

// Round 11
// 2209.793 us; speedup vs baseline: 1.9935x; 1.1393x over previous
//
#include <hip/hip_runtime.h>
#include <math.h>

// ---- problem constants ----
#define C_      3
#define H_      224
#define W_      224
#define KH_     14
#define KW_     14
#define NPATCH  196
#define PELEMS  768
#define D_      768
#define HEADS_  12
#define Y_      64
#define MHID    3072
#define NMASK   100
#define NSTEPS  12
#define ALPHA_  0.1f
#define BETA_   0.125f
#define EPS_    1e-5f
#define B_      16
#define NTOK    197
#define ROWS    (B_*NTOK)   /* 3152 real rows */
#define MPAD    3200        /* 50 * 64 */
#define QKLD    1536        /* fused q|k leading dim */
#define PACKLD  4608        /* hid(3072) | Gq(768) | Gk(768) */
#define W2LD    4608        /* qk(1536) | hid(3072) fused B rows */
#define PMP     228         /* LDS P pitch (fp32) */
#define PPITCH  224         /* global P/PT/kT/qT pitch (bf16), 7*32 */
#define KSPLIT  4           /* grad GEMM split-K (4608/4=1152=18*64) */

typedef short short8 __attribute__((ext_vector_type(8)));
typedef unsigned short ushort8 __attribute__((ext_vector_type(8)));
typedef float floatx4 __attribute__((ext_vector_type(4)));

__device__ __forceinline__ unsigned short f2bf(float f) {
    union { float f; unsigned u; } v; v.f = f;
    unsigned r = (v.u + 0x7FFFu + ((v.u >> 16) & 1u)) >> 16;
    return (unsigned short)r;
}
__device__ __forceinline__ float bf2f(unsigned short u) {
    union { unsigned u; float f; } v; v.u = ((unsigned)u) << 16;
    return v.f;
}

__device__ __forceinline__ void async_cp16(const void* g, void* l) {
    __builtin_amdgcn_global_load_lds(
        (const __attribute__((address_space(1))) unsigned int*)g,
        (__attribute__((address_space(3))) unsigned int*)l, 16, 0, 0);
}

// ---------------------------------------------------------------------------
// MFMA bf16 NT GEMM: C[M][N] = A(MxK bf16) @ B(NxK bf16)^T.
// 64x128 tile, BK=64/iter, global_load_lds staging (r10 proven; register
// prefetch spills to scratch — r8; 128x128 tile is grid-starved — r7-r9).
// OUT_MODE: 0 = fp32 store, 1 = bf16 store,
//           3 = split epilogue: col<1536 -> Cout bf16 (ld QKLD), else relu ->
//               Cout2 bf16 (ld PACKLD, col-1536)
//           4 = split-K: koff = blockIdx.z*K, atomicAdd(Cout, ALPHA*v) fp32
template<int OUT_MODE, bool RELU, bool HAS_BIAS>
__global__ __launch_bounds__(256) void mfma_gemm(
    const unsigned short* __restrict__ A, int lda,
    const unsigned short* __restrict__ B, int ldb,
    void* __restrict__ Cout, int ldc, void* __restrict__ Cout2,
    const float* __restrict__ bias, int K)
{
    __shared__ alignas(16) unsigned short ldsA[2][64 * 32];
    __shared__ alignas(16) unsigned short ldsB[2][128 * 32];

    const int bx = blockIdx.x, by = blockIdx.y;
    const int koff = (OUT_MODE == 4) ? blockIdx.z * K : 0;

    const int t    = threadIdx.x;
    const int wave = t >> 6;
    const int lane = t & 63;
    const int row0 = by << 6;
    const int col0 = bx << 7;
    const int wm = (wave & 1) << 5;
    const int wn = (wave >> 1) << 6;
    const int r  = lane & 15;
    const int qd = lane >> 4;

    const unsigned short* Abase = A + (size_t)row0 * lda + koff;
    const unsigned short* Bbase = B + (size_t)col0 * ldb + koff;

    floatx4 acc[2][4];
#pragma unroll
    for (int i = 0; i < 2; ++i)
#pragma unroll
        for (int j = 0; j < 4; ++j)
            acc[i][j] = (floatx4){0.f, 0.f, 0.f, 0.f};

    const int crow = t >> 2;
    const int coff = (t & 3) << 3;
    for (int k0 = 0; k0 < K; k0 += 64) {
#pragma unroll
        for (int kb = 0; kb < 2; ++kb) {
            const int kk = k0 + kb * 32;
            async_cp16(Abase + (size_t)crow * lda + kk + coff,
                       ldsA[kb] + (wave << 9));
            async_cp16(Bbase + (size_t)crow * ldb + kk + coff,
                       ldsB[kb] + (wave << 9));
            async_cp16(Bbase + (size_t)(64 + crow) * ldb + kk + coff,
                       ldsB[kb] + 2048 + (wave << 9));
        }
        __syncthreads();
#pragma unroll
        for (int kb = 0; kb < 2; ++kb) {
            short8 af[2], bfr[4];
#pragma unroll
            for (int i = 0; i < 2; ++i)
                af[i]  = *(const short8*)&ldsA[kb][(wm + (i << 4) + r) * 32 + (qd << 3)];
#pragma unroll
            for (int j = 0; j < 4; ++j)
                bfr[j] = *(const short8*)&ldsB[kb][(wn + (j << 4) + r) * 32 + (qd << 3)];
#pragma unroll
            for (int i = 0; i < 2; ++i)
#pragma unroll
                for (int j = 0; j < 4; ++j)
                    acc[i][j] = __builtin_amdgcn_mfma_f32_16x16x32_bf16(
                                    af[i], bfr[j], acc[i][j], 0, 0, 0);
        }
        __syncthreads();
    }

#pragma unroll
    for (int i = 0; i < 2; ++i) {
#pragma unroll
        for (int j = 0; j < 4; ++j) {
            int cc = col0 + wn + (j << 4) + r;
#pragma unroll
            for (int reg = 0; reg < 4; ++reg) {
                int rr = row0 + wm + (i << 4) + (qd << 2) + reg;
                float v = acc[i][j][reg];
                if (HAS_BIAS) v += bias[cc];
                if (RELU)     v = fmaxf(v, 0.f);
                if (OUT_MODE == 1)
                    ((unsigned short*)Cout)[(size_t)rr * ldc + cc] = f2bf(v);
                else if (OUT_MODE == 3) {
                    if (cc < QKLD)
                        ((unsigned short*)Cout)[(size_t)rr * QKLD + cc] = f2bf(v);
                    else
                        ((unsigned short*)Cout2)[(size_t)rr * PACKLD + (cc - QKLD)]
                            = f2bf(fmaxf(v, 0.f));
                } else if (OUT_MODE == 4)
                    atomicAdd(&((float*)Cout)[(size_t)rr * ldc + cc], ALPHA_ * v);
                else
                    ((float*)Cout)[(size_t)rr * ldc + cc] = v;
            }
        }
    }
}

// ---------------------------------------------------------------------------
// Per-head transpose: qT[bh][y][n] = q[b*197+n][h*64+y], kT likewise (from
// the k half). m>=197 cols written as zeros (K-dim padding for attn_pv).
__global__ __launch_bounds__(256) void tqk_kernel(
    const unsigned short* __restrict__ qk,
    unsigned short* __restrict__ qT,
    unsigned short* __restrict__ kT)
{
    const int bh = blockIdx.x;
    const int h = bh % HEADS_, b = bh / HEADS_;
    const int m0 = blockIdx.y << 6;        // 0,64,128,192
    const int t = threadIdx.x;
    __shared__ alignas(16) unsigned short tile[64 * 72];
    const size_t rowbase = (size_t)(b * NTOK) * QKLD;

    for (int pass = 0; pass < 2; ++pass) {
        const int srcoff = (pass ? 768 : 0) + h * 64;
        unsigned short* dst = (pass ? kT : qT) + (size_t)bh * 64 * PPITCH;
        __syncthreads();
        for (int idx = t; idx < 64 * 8; idx += 256) {
            int mr = idx >> 3, c8 = idx & 7;
            uint4 v = (uint4){0, 0, 0, 0};
            if (m0 + mr < NTOK)
                v = *(const uint4*)&qk[rowbase + (size_t)(m0 + mr) * QKLD + srcoff + c8 * 8];
            *(uint4*)&tile[mr * 72 + c8 * 8] = v;
        }
        __syncthreads();
        {
            int y = t >> 2, mg = t & 3;
            if (m0 + mg * 16 < PPITCH) {
                unsigned short* drow = dst + (size_t)y * PPITCH + m0 + mg * 16;
#pragma unroll
                for (int c = 0; c < 8; ++c) {
                    unsigned lo = tile[(mg * 16 + 2 * c) * 72 + y];
                    unsigned hi = tile[(mg * 16 + 2 * c + 1) * 72 + y];
                    *(unsigned*)&drow[2 * c] = lo | (hi << 16);
                }
            }
        }
    }
}

// ---------------------------------------------------------------------------
// Attention A: per (bh, 32-q-row chunk): S = Q K^T via MFMA, softmax (beta in
// exp), write P[bh][n][m] and PT[bh][m][n] (bf16, pitch 224, K-dims zeroed).
__global__ __launch_bounds__(256) void attn_pgq_kernel(
    const unsigned short* __restrict__ qk,   // bf16 [MPAD][1536]
    unsigned short* __restrict__ P,          // [192][224][224]
    unsigned short* __restrict__ PT)         // [192][224][224]
{
    const int bh = blockIdx.x;
    const int h = bh % HEADS_, b = bh / HEADS_;
    const int n0 = blockIdx.y << 5;
    const int csz = (NTOK - n0 < 32) ? (NTOK - n0) : 32;
    const int t = threadIdx.x;
    const int lane = t & 63, wave = t >> 6;
    const int ln15 = lane & 15, quad = lane >> 4;

    __shared__ alignas(16) unsigned short KsS[208 * 72];  // K_h m-major
    __shared__ alignas(16) unsigned short QcS[32 * 72];   // Q chunk
    __shared__ alignas(16) float Pm[32 * PMP];            // S/P fp32

    const size_t rowbase = (size_t)(b * NTOK) * QKLD;
    const int hoff = h * 64;

    for (int idx = t; idx < NTOK * 8; idx += 256) {
        int m = idx >> 3, c8 = idx & 7;
        *(uint4*)&KsS[m * 72 + c8 * 8] =
            *(const uint4*)&qk[rowbase + (size_t)m * QKLD + 768 + hoff + c8 * 8];
    }
    for (int idx = t; idx < 88; idx += 256) {
        int m = 197 + (idx >> 3), c8 = idx & 7;
        *(uint4*)&KsS[m * 72 + c8 * 8] = (uint4){0, 0, 0, 0};
    }
    for (int idx = t; idx < csz * 8; idx += 256) {
        int nn = idx >> 3, c8 = idx & 7;
        *(uint4*)&QcS[nn * 72 + c8 * 8] =
            *(const uint4*)&qk[rowbase + (size_t)(n0 + nn) * QKLD + hoff + c8 * 8];
    }
    __syncthreads();

    // ---- S = Q K^T via MFMA ----
    {
        short8 aq[2][2];
#pragma unroll
        for (int mt = 0; mt < 2; ++mt)
#pragma unroll
            for (int kb = 0; kb < 2; ++kb)
                aq[mt][kb] = *(const short8*)
                    &QcS[(mt * 16 + ln15) * 72 + kb * 32 + quad * 8];

        for (int nt = wave; nt < 13; nt += 4) {
            short8 b0 = *(const short8*)&KsS[(nt * 16 + ln15) * 72 + quad * 8];
            short8 b1 = *(const short8*)&KsS[(nt * 16 + ln15) * 72 + 32 + quad * 8];
            floatx4 s0 = (floatx4){0.f, 0.f, 0.f, 0.f};
            floatx4 s1 = (floatx4){0.f, 0.f, 0.f, 0.f};
            s0 = __builtin_amdgcn_mfma_f32_16x16x32_bf16(aq[0][0], b0, s0, 0, 0, 0);
            s0 = __builtin_amdgcn_mfma_f32_16x16x32_bf16(aq[0][1], b1, s0, 0, 0, 0);
            s1 = __builtin_amdgcn_mfma_f32_16x16x32_bf16(aq[1][0], b0, s1, 0, 0, 0);
            s1 = __builtin_amdgcn_mfma_f32_16x16x32_bf16(aq[1][1], b1, s1, 0, 0, 0);
#pragma unroll
            for (int reg = 0; reg < 4; ++reg) {
                Pm[(quad * 4 + reg) * PMP + nt * 16 + ln15]        = s0[reg];
                Pm[(16 + quad * 4 + reg) * PMP + nt * 16 + ln15]   = s1[reg];
            }
        }
    }
    __syncthreads();

    // ---- softmax rows (beta applied inside exp) ----
    for (int nn = wave; nn < csz; nn += 4) {
        float v0 = Pm[nn * PMP + lane];
        float v1 = (lane +  64 < NTOK) ? Pm[nn * PMP + lane +  64] : -1e30f;
        float v2 = (lane + 128 < NTOK) ? Pm[nn * PMP + lane + 128] : -1e30f;
        float v3 = (lane + 192 < NTOK) ? Pm[nn * PMP + lane + 192] : -1e30f;
        float mx = fmaxf(fmaxf(v0, v1), fmaxf(v2, v3));
#pragma unroll
        for (int o = 32; o > 0; o >>= 1) mx = fmaxf(mx, __shfl_xor(mx, o, 64));
        float e0 = __expf((v0 - mx) * BETA_);
        float e1 = (lane +  64 < NTOK) ? __expf((v1 - mx) * BETA_) : 0.f;
        float e2 = (lane + 128 < NTOK) ? __expf((v2 - mx) * BETA_) : 0.f;
        float e3 = (lane + 192 < NTOK) ? __expf((v3 - mx) * BETA_) : 0.f;
        float s = e0 + e1 + e2 + e3;
#pragma unroll
        for (int o = 32; o > 0; o >>= 1) s += __shfl_xor(s, o, 64);
        float inv = 1.0f / s;
        Pm[nn * PMP + lane] = e0 * inv;
        if (lane +  64 < NTOK) Pm[nn * PMP + lane +  64] = e1 * inv;
        if (lane + 128 < NTOK) Pm[nn * PMP + lane + 128] = e2 * inv;
        if (lane + 192 < NTOK) Pm[nn * PMP + lane + 192] = e3 * inv;
    }
    __syncthreads();

    // ---- write P rows (m-pads zero) ----
    if (t < PPITCH) {
        for (int nn = 0; nn < csz; ++nn) {
            unsigned short v = (t < NTOK) ? f2bf(Pm[nn * PMP + t]) : (unsigned short)0;
            P[((size_t)bh * PPITCH + n0 + nn) * PPITCH + t] = v;
        }
    }
    // ---- write PT cols (32-wide n-chunk; nn>=csz and m>=197 zeroed) ----
    if (t < PPITCH) {
        unsigned short* drow = &PT[((size_t)bh * PPITCH + t) * PPITCH + n0];
        bool mreal = (t < NTOK);
#pragma unroll
        for (int c = 0; c < 16; ++c) {
            unsigned lo = (mreal && 2 * c     < csz) ? f2bf(Pm[(2 * c    ) * PMP + t]) : 0u;
            unsigned hi = (mreal && 2 * c + 1 < csz) ? f2bf(Pm[(2 * c + 1) * PMP + t]) : 0u;
            *(unsigned*)&drow[2 * c] = lo | (hi << 16);
        }
    }
}

// ---------------------------------------------------------------------------
// Attention B (MFMA): grid (192, 2, 2).
// sel=0: Gq[n][y] = sum_m P[n][m] kT[y][m]  -> pack cols 3072+
// sel=1: Gk[m][y] = sum_n PT[m][n] qT[y][n] -> pack cols 3840+
// K-dim padded to 224 with zeros (P/PT/kT/qT pads). B staged in LDS; A-frags
// loaded directly from global. z splits output rows (112 each).
__global__ __launch_bounds__(256) void attn_pv_kernel(
    const unsigned short* __restrict__ P,
    const unsigned short* __restrict__ PT,
    const unsigned short* __restrict__ kT,
    const unsigned short* __restrict__ qT,
    unsigned short* __restrict__ pack)
{
    const int bh = blockIdx.x;
    const int h = bh % HEADS_, b = bh / HEADS_;
    const int sel = blockIdx.y;
    const int mbase = blockIdx.z * 112;
    const int t = threadIdx.x;
    const int lane = t & 63, wave = t >> 6;
    const int ln15 = lane & 15, quad = lane >> 4;

    const unsigned short* Abase = (sel ? PT : P) + (size_t)bh * PPITCH * PPITCH;
    const unsigned short* Bv    = (sel ? qT : kT) + (size_t)bh * 64 * PPITCH;
    const int colbase = sel ? 3840 : 3072;

    __shared__ alignas(16) unsigned short Bs[64 * 232];
    for (int idx = t; idx < 64 * 28; idx += 256) {
        int y = idx / 28, c = idx % 28;
        *(uint4*)&Bs[y * 232 + c * 8] = *(const uint4*)&Bv[(size_t)y * PPITCH + c * 8];
    }
    __syncthreads();

    floatx4 acc[7];
#pragma unroll
    for (int i = 0; i < 7; ++i) acc[i] = (floatx4){0.f, 0.f, 0.f, 0.f};

    for (int kb = 0; kb < 7; ++kb) {
        short8 bf = *(const short8*)&Bs[(wave * 16 + ln15) * 232 + kb * 32 + quad * 8];
#pragma unroll
        for (int i = 0; i < 7; ++i) {
            short8 af = *(const short8*)
                &Abase[(size_t)(mbase + i * 16 + ln15) * PPITCH + kb * 32 + quad * 8];
            acc[i] = __builtin_amdgcn_mfma_f32_16x16x32_bf16(af, bf, acc[i], 0, 0, 0);
        }
    }

    const int coln = colbase + h * 64 + wave * 16 + ln15;
#pragma unroll
    for (int i = 0; i < 7; ++i) {
#pragma unroll
        for (int reg = 0; reg < 4; ++reg) {
            int rowm = mbase + i * 16 + quad * 4 + reg;
            if (rowm < NTOK)
                pack[(size_t)(b * NTOK + rowm) * PACKLD + coln] = f2bf(acc[i][reg]);
        }
    }
}

// ---------------------------------------------------------------------------
// setup conversions
__global__ __launch_bounds__(256) void w2pack_kernel(const float* __restrict__ Wq,
                                                     const float* __restrict__ Wk,
                                                     const float* __restrict__ Xi,
                                                     unsigned short* __restrict__ out)
{
    int idx = blockIdx.x * 256 + threadIdx.x;          // n*768 + d
    int d = idx % D_, n = idx / D_;
    float v;
    if (n < 768)       v = Wq[((size_t)(n >> 6) * D_ + d) * Y_ + (n & 63)];
    else if (n < 1536) { int e = n - 768; v = Wk[((size_t)(e >> 6) * D_ + d) * Y_ + (e & 63)]; }
    else               v = Xi[(size_t)d * MHID + (n - 1536)];
    out[idx] = f2bf(v);
}

__global__ __launch_bounds__(256) void bpack_kernel(const float* __restrict__ Xi,
                                                    const float* __restrict__ Wq,
                                                    const float* __restrict__ Wk,
                                                    unsigned short* __restrict__ out)
{
    int idx = blockIdx.x * 256 + threadIdx.x;          // d*4608 + c
    int c = idx % PACKLD, d = idx / PACKLD;
    float v;
    if (c < 3072)       v = Xi[(size_t)d * MHID + c];
    else if (c < 3840)  { int e = c - 3072; v = Wq[((size_t)(e >> 6) * D_ + d) * Y_ + (e & 63)]; }
    else                { int e = c - 3840; v = Wk[((size_t)(e >> 6) * D_ + d) * Y_ + (e & 63)]; }
    out[idx] = f2bf(v);
}

__global__ __launch_bounds__(256) void t768_kernel(const float* __restrict__ in,
                                                   unsigned short* __restrict__ out)
{
    int idx = blockIdx.x * 256 + threadIdx.x;          // n*768 + k
    int k = idx % D_, n = idx / D_;
    out[idx] = f2bf(in[(size_t)k * D_ + n]);
}

// ---------------------------------------------------------------------------
__global__ void mask_flags_kernel(const int* __restrict__ mask, int* __restrict__ flags)
{
    int b = threadIdx.x;
    if (b >= B_) return;
    const int* mb = mask + b * NPATCH;
    int* fb = flags + b * NPATCH;
    int cnt = 0;
    for (int n = 0; n < NPATCH; ++n) {
        int mv = mb[n];
        fb[n] = (mv == 1 && cnt < NMASK) ? 1 : 0;
        cnt += (mv == 1);
    }
    if (cnt < NMASK) fb[0] = 1;
}

__global__ __launch_bounds__(256) void patchify_kernel(const float* __restrict__ img,
                                                       unsigned short* __restrict__ patch)
{
    int idx = blockIdx.x * 256 + threadIdx.x;          // row*768 + e
    int e = idx % PELEMS, row = idx / PELEMS;
    int b = row / NPATCH, n = row % NPATCH;
    int kh = n / KW_, kw = n % KW_;
    int c = e >> 8, p = (e >> 4) & 15, q2 = e & 15;
    patch[idx] = f2bf(img[(((size_t)b * C_ + c) * H_ + kh * 16 + p) * W_ + kw * 16 + q2]);
}

__global__ __launch_bounds__(256) void build_x_kernel(const float* __restrict__ tok,
                                                      const int* __restrict__ flags,
                                                      const float* __restrict__ cls,
                                                      const float* __restrict__ mtok,
                                                      const float* __restrict__ pos,
                                                      float* __restrict__ x)
{
    int row = blockIdx.x;
    int b = row / NTOK, rr = row % NTOK;
    int tid = threadIdx.x;
#pragma unroll
    for (int i = 0; i < 3; ++i) {
        int d = tid + (i << 8);
        float v;
        if (rr == 0) v = cls[d];
        else {
            int n = rr - 1;
            v = flags[b * NPATCH + n] ? mtok[d]
                                      : tok[((size_t)b * NPATCH + n) * D_ + d];
        }
        x[(size_t)row * D_ + d] = v + pos[(size_t)rr * D_ + d];
    }
}

__global__ __launch_bounds__(256) void lnorm_kernel(const float* __restrict__ x,
                                                    unsigned short* __restrict__ g,
                                                    const float* __restrict__ gamma,
                                                    const float* __restrict__ delta)
{
    int row = blockIdx.x, tid = threadIdx.x;
    const float* xr = x + (size_t)row * D_;
    float v0 = xr[tid], v1 = xr[tid + 256], v2 = xr[tid + 512];

    __shared__ float red[256];
    red[tid] = v0 + v1 + v2;
    __syncthreads();
    for (int off = 128; off > 0; off >>= 1) {
        if (tid < off) red[tid] += red[tid + off];
        __syncthreads();
    }
    float mean = red[0] * (1.0f / D_);
    __syncthreads();
    float a0 = v0 - mean, a1 = v1 - mean, a2 = v2 - mean;
    red[tid] = a0 * a0 + a1 * a1 + a2 * a2;
    __syncthreads();
    for (int off = 128; off > 0; off >>= 1) {
        if (tid < off) red[tid] += red[tid + off];
        __syncthreads();
    }
    float var = red[0] * (1.0f / D_);
    float inv = gamma[0] / sqrtf(var + EPS_);
    unsigned short* gr = g + (size_t)row * D_;
    gr[tid]       = f2bf(a0 * inv + delta[tid]);
    gr[tid + 256] = f2bf(a1 * inv + delta[tid + 256]);
    gr[tid + 512] = f2bf(a2 * inv + delta[tid + 512]);
}

// ---------------------------------------------------------------------------
__global__ __launch_bounds__(256) void unpatch_kernel(const float* __restrict__ dec,
                                                      float* __restrict__ out)
{
    int idx = blockIdx.x * 256 + threadIdx.x;
    int ww = idx % W_;
    int t2 = idx / W_;
    int hh = t2 % H_;
    int t3 = t2 / H_;
    int c  = t3 % C_;
    int b  = t3 / C_;
    int kh = hh >> 4, p = hh & 15, kw = ww >> 4, q2 = ww & 15;
    int n = kh * KW_ + kw;
    int e = (c << 8) + (p << 4) + q2;
    out[idx] = dec[((size_t)b * NTOK + 1 + n) * D_ + e];
}

// ---------------------------------------------------------------------------
extern "C" void kernel_launch(void* const* d_in, const int* in_sizes, int n_in,
                              void* d_out, int out_size, void* d_ws, size_t ws_size,
                              hipStream_t stream)
{
    const float* img   = (const float*)d_in[0];
    const int*   mask  = (const int*)d_in[1];
    const float* enc_W = (const float*)d_in[2];
    const float* enc_b = (const float*)d_in[3];
    const float* dec_W = (const float*)d_in[4];
    const float* dec_b = (const float*)d_in[5];
    const float* cls   = (const float*)d_in[6];
    const float* mtok  = (const float*)d_in[7];
    const float* pos   = (const float*)d_in[8];
    const float* Wq    = (const float*)d_in[9];
    const float* Wk    = (const float*)d_in[10];
    const float* Xi    = (const float*)d_in[11];
    const float* gamma = (const float*)d_in[12];
    const float* delta = (const float*)d_in[13];
    float* out = (float*)d_out;

    float* ws = (float*)d_ws;
    size_t off = 0;
    auto alloc = [&](size_t nfloats) {
        off = (off + 63) & ~(size_t)63;
        float* p = ws + off; off += nfloats; return p;
    };
    float*          x    = alloc((size_t)MPAD * D_);                  // fp32
    unsigned short* g    = (unsigned short*)alloc((size_t)MPAD * D_ / 2);
    // qk bf16 [MPAD][1536]; bytes reused as dec fp32 [MPAD][768] at the end
    unsigned short* qkg  = (unsigned short*)alloc((size_t)MPAD * QKLD / 2);
    float*          decb = (float*)qkg;
    unsigned short* pack = (unsigned short*)alloc((size_t)MPAD * PACKLD / 2);
    unsigned short* Pbuf = (unsigned short*)alloc((size_t)192 * PPITCH * PPITCH / 2);
    unsigned short* PTb  = (unsigned short*)alloc((size_t)192 * PPITCH * PPITCH / 2);
    unsigned short* kT   = (unsigned short*)alloc((size_t)192 * 64 * PPITCH / 2);
    unsigned short* qT   = (unsigned short*)alloc((size_t)192 * 64 * PPITCH / 2);
    unsigned short* W2   = (unsigned short*)alloc((size_t)W2LD * D_ / 2);
    unsigned short* Bpk  = (unsigned short*)alloc((size_t)D_ * PACKLD / 2);
    unsigned short* decT = (unsigned short*)alloc((size_t)D_ * D_ / 2);
    unsigned short* encT = (unsigned short*)alloc((size_t)D_ * D_ / 2);
    int*            flags = (int*)alloc(B_ * NPATCH);
    // setup-phase overlays inside pack (dead until first hid GEMM)
    unsigned short* patch = pack;                                // MPAD x 768 bf16
    float*          tok   = (float*)(pack + (size_t)MPAD * D_);  // MPAD x 768 fp32

    const dim3 blk(256);

    // ---- one-time packs ----
    w2pack_kernel<<<dim3(W2LD * D_ / 256), blk, 0, stream>>>(Wq, Wk, Xi, W2);
    bpack_kernel<<<dim3(D_ * PACKLD / 256), blk, 0, stream>>>(Xi, Wq, Wk, Bpk);
    t768_kernel<<<dim3(D_ * D_ / 256), blk, 0, stream>>>(dec_W, decT);
    t768_kernel<<<dim3(D_ * D_ / 256), blk, 0, stream>>>(enc_W, encT);
    mask_flags_kernel<<<dim3(1), dim3(64), 0, stream>>>(mask, flags);

    // ---- encode + build x ----
    patchify_kernel<<<dim3(B_ * NPATCH * PELEMS / 256), blk, 0, stream>>>(img, patch);
    mfma_gemm<0, false, true><<<dim3(D_ / 128, MPAD / 64), blk, 0, stream>>>(
        patch, PELEMS, encT, PELEMS, tok, D_, nullptr, enc_b, PELEMS);
    build_x_kernel<<<dim3(ROWS), blk, 0, stream>>>(tok, flags, cls, mtok, pos, x);

    // ---- energy-descent loop ----
    for (int step = 0; step < NSTEPS; ++step) {
        lnorm_kernel<<<dim3(ROWS), blk, 0, stream>>>(x, g, gamma, delta);
        // [qk | hid] = g @ [Wq|Wk|Xi]  (split epilogue)
        mfma_gemm<3, false, false><<<dim3(W2LD / 128, MPAD / 64), blk, 0, stream>>>(
            g, D_, W2, D_, qkg, QKLD, pack, nullptr, D_);
        // per-head transposed q/k for the PV MFMAs
        tqk_kernel<<<dim3(B_ * HEADS_, 4), blk, 0, stream>>>(qkg, qT, kT);
        // S + softmax -> P, PT
        attn_pgq_kernel<<<dim3(B_ * HEADS_, 7), blk, 0, stream>>>(qkg, Pbuf, PTb);
        // Gq = P K, Gk = P^T Q  (MFMA) -> pack cols 3072..4607
        attn_pv_kernel<<<dim3(B_ * HEADS_, 2, 2), blk, 0, stream>>>(
            Pbuf, PTb, kT, qT, pack);
        // x += ALPHA * ([hid|Gq|Gk] @ [Xi|Wq|Wk]^T)  (split-K x4, atomic)
        mfma_gemm<4, false, false><<<dim3(D_ / 128, MPAD / 64, KSPLIT), blk, 0, stream>>>(
            pack, PACKLD, Bpk, PACKLD, x, D_, nullptr, nullptr, PACKLD / KSPLIT);
    }

    // ---- decode + unpatchify ----
    lnorm_kernel<<<dim3(ROWS), blk, 0, stream>>>(x, g, gamma, delta);
    mfma_gemm<0, false, true><<<dim3(D_ / 128, MPAD / 64), blk, 0, stream>>>(
        g, D_, decT, D_, decb, D_, nullptr, dec_b, D_);
    unpatch_kernel<<<dim3(B_ * C_ * H_ * W_ / 256), blk, 0, stream>>>(decb, out);
}